// Round 8
// baseline (333.551 us; speedup 1.0000x reference)
//
#include <hip/hip_runtime.h>
#include <hip/hip_bf16.h>
#include <math.h>

// bf16 stored as short (raw bits); fp32 accumulate in MFMA.
using bf16x8 = __attribute__((ext_vector_type(8))) short;
using f32x4  = __attribute__((ext_vector_type(4))) float;
using f32x16 = __attribute__((ext_vector_type(16))) float;
using i32x4  = __attribute__((ext_vector_type(4))) int;
using i32x2  = __attribute__((ext_vector_type(2))) int;

#define MFMA_BF16(a, b, c) __builtin_amdgcn_mfma_f32_16x16x32_bf16((a), (b), (c), 0, 0, 0)
#define MFMA32(a, b, c)    __builtin_amdgcn_mfma_f32_32x32x16_bf16((a), (b), (c), 0, 0, 0)

__device__ __forceinline__ float bf2f(short s) {
    union { unsigned u; float f; } v;
    v.u = ((unsigned)(unsigned short)s) << 16;
    return v.f;
}
__device__ __forceinline__ short f2bf(float f) {
    union { float f; unsigned u; } v; v.f = f;
    unsigned r = v.u + 0x7FFF + ((v.u >> 16) & 1);  // round-to-nearest-even
    return (short)(r >> 16);
}
// Native packed f32->bf16 convert (RNE), 1 VALU op for 2 values.
__device__ __forceinline__ int cvtpk_bf16(float lo, float hi) {
    int r;
    asm("v_cvt_pk_bf16_f32 %0, %1, %2" : "=v"(r) : "v"(lo), "v"(hi));
    return r;
}
// v_permlane32_swap_b32: a'[l<32]=a[l], a'[32+i]=b[i]; b'[i]=a[32+i], b'[32+i]=b[32+i].
__device__ __forceinline__ void permswap(int &a, int &b) {
#if __has_builtin(__builtin_amdgcn_permlane32_swap)
    typedef unsigned u32x2v __attribute__((ext_vector_type(2)));
    u32x2v r = __builtin_amdgcn_permlane32_swap((unsigned)a, (unsigned)b, false, false);
    a = (int)r[0]; b = (int)r[1];
#else
    asm volatile("v_permlane32_swap_b32 %0, %1" : "+v"(a), "+v"(b));
#endif
}
// Raw 2^x (v_exp_f32). Q is pre-scaled by log2(e)/8 so this IS exp(score).
__device__ __forceinline__ float fexp2(float x) {
#if __has_builtin(__builtin_amdgcn_exp2f)
    return __builtin_amdgcn_exp2f(x);
#else
    return exp2f(x);
#endif
}

// Async global->LDS DMA, 16B per lane (LDS dest = wave base + lane*16).
__device__ __forceinline__ void gload_lds16(const void* g, void* l) {
    __builtin_amdgcn_global_load_lds(
        (const __attribute__((address_space(1))) void*)g,
        (__attribute__((address_space(3))) void*)l, 16, 0, 0);
}

// ---------------------------------------------------------------------------
// Input dtype detector (proven R3). flag: 1=bf16, 0=fp32.
// ---------------------------------------------------------------------------
__global__ void detect_dtype(const unsigned short* __restrict__ emb, int* flag) {
    __shared__ int tot;
    if (threadIdx.x == 0) tot = 0;
    __syncthreads();
    int c = 0;
    for (int i = 0; i < 64; i++) {
        unsigned short v = emb[2 * (threadIdx.x * 64 + i)];
        unsigned e = (v >> 7) & 0xFF;
        if (v == 0 || v == 0x8000u || (e >= 97 && e <= 137)) c++;
    }
    atomicAdd(&tot, c);
    __syncthreads();
    if (threadIdx.x == 0) *flag = (tot > 8192) ? 1 : 0;
}

__global__ void convert8(const void* __restrict__ src, short* __restrict__ dst,
                         int n8, const int* __restrict__ flag) {
    int i = blockIdx.x * 256 + threadIdx.x;
    if (i >= n8) return;
    if (*flag) {
        ((bf16x8*)dst)[i] = ((const bf16x8*)src)[i];
    } else {
        const float* f = (const float*)src + (size_t)i * 8;
        bf16x8 o;
#pragma unroll
        for (int j = 0; j < 8; j++) o[j] = f2bf(f[j]);
        ((bf16x8*)dst)[i] = o;
    }
}

// All 4 weights (131072 n8 each) + 4 biases (128 n8 each) in ONE launch.
// Grid = 2050 blocks x 256 = 524800 = 4*131072 + 4*128 exactly.
__global__ void convert_all(
    const void* __restrict__ w0, const void* __restrict__ w1,
    const void* __restrict__ w2, const void* __restrict__ w3,
    const void* __restrict__ b0, const void* __restrict__ b1,
    const void* __restrict__ b2, const void* __restrict__ b3,
    short* dw0, short* dw1, short* dw2, short* dw3,
    short* db0, short* db1, short* db2, short* db3,
    const int* __restrict__ flag)
{
    int i = blockIdx.x * 256 + threadIdx.x;
    const void* src; short* dst; int idx;
    if (i < 524288) {
        int w = i >> 17; idx = i & 131071;
        src = (w == 0) ? w0 : (w == 1) ? w1 : (w == 2) ? w2 : w3;
        dst = (w == 0) ? dw0 : (w == 1) ? dw1 : (w == 2) ? dw2 : dw3;
    } else {
        int j = i - 524288; int b = j >> 7; idx = j & 127;
        src = (b == 0) ? b0 : (b == 1) ? b1 : (b == 2) ? b2 : b3;
        dst = (b == 0) ? db0 : (b == 1) ? db1 : (b == 2) ? db2 : db3;
    }
    if (*flag) {
        ((bf16x8*)dst)[idx] = ((const bf16x8*)src)[idx];
    } else {
        const float* f = (const float*)src + (size_t)idx * 8;
        bf16x8 o;
#pragma unroll
        for (int j = 0; j < 8; j++) o[j] = f2bf(f[j]);
        ((bf16x8*)dst)[idx] = o;
    }
}

// ---------------------------------------------------------------------------
// GEMM R14: 128x128 tile, BK=32, mfma_32x32x16 inner + ring-3 prefetch.
//  - MFMA32: 8 mfma/K-step (vs 16 of 16x16x32) for the same FLOP -> halved
//    MFMA issue slots. Fragment contract HW-verified by this session's attn:
//    A/B lane&31 = m/n, k = (lane>>5)*8+j; C/D col=lane&31,
//    row=(r&3)+8*(r>>2)+4*hi.
//  - Ring-3 LDS (48 KB, 3 blocks/CU), 2 tiles in flight, s_waitcnt vmcnt(8):
//    ~2 compute phases (~300 cy) cover L2 latency (~200 cy); depth-1 only
//    covered ~150 cy.
//  - Matched swizzle for the 32x32 read pattern (row stride 64B, lane=row):
//    LDS row r chunk c holds global chunk c^(r&3); stage source chunk
//    (l&3)^((l>>2)&3); read chunk (2s+hi)^(l31&3). Enumerated: all 8
//    16B-slots x 8 lanes -> conflict-free.
//  - XCD swizzle: swz=(bid&7)*64+(bid>>3) (each XCD: 8 m-panels, L2-resident).
// mode: 0 = bf16 natural, 1 = bf16 transposed (Vt), 2 = per *flag dtype.
// ---------------------------------------------------------------------------
__global__ __launch_bounds__(256) void gemm128(
    const short* __restrict__ A,
    const short* __restrict__ B0, const short* __restrict__ B1,
    const short* __restrict__ B2,
    const short* __restrict__ bias0, const short* __restrict__ bias1,
    const short* __restrict__ bias2,
    void* __restrict__ C0, void* __restrict__ C1, void* __restrict__ C2,
    float s0, float s1, float s2,
    int mode0, int mode1, int mode2,
    const int* __restrict__ flag)
{
    constexpr int M = 8192, N = 1024, Kd = 1024, BK = 32;
    __shared__ __align__(16) short As[3][128 * BK];
    __shared__ __align__(16) short Bs[3][128 * BK];

    const int z = blockIdx.z;
    const short* B    = (z == 0) ? B0    : (z == 1) ? B1    : B2;
    const short* bias = (z == 0) ? bias0 : (z == 1) ? bias1 : bias2;
    void*  C     = (z == 0) ? C0 : (z == 1) ? C1 : C2;
    float  scale = (z == 0) ? s0 : (z == 1) ? s1 : s2;
    int    mode  = (z == 0) ? mode0 : (z == 1) ? mode1 : mode2;

    const int tid  = threadIdx.x;
    const int lane = tid & 63;
    const int wave = tid >> 6;
    const int l31  = lane & 31;
    const int hi   = lane >> 5;

    // XCD-aware bijective swizzle (512 blocks, 8 XCDs; XCD = bid%8).
    const int bid = blockIdx.x;
    const int swz = ((bid & 7) << 6) | (bid >> 3);
    const int m0 = (swz >> 3) * 128;
    const int n0 = (swz & 7) * 128;
    const int wm = (wave >> 1) * 64;
    const int wn = (wave & 1) * 64;

    // staging: lane l -> row l>>2, LDS chunk l&3; source chunk = (l&3)^((l>>2)&3)
    const int srow = lane >> 2;
    const int scol = ((lane & 3) ^ ((lane >> 2) & 3)) * 8;
    // fragment read chunk (16B units, shorts offset): (2s+hi) ^ (l31&3)
    const int xr = l31 & 3;

    int fl = 1;
    if (mode == 2) fl = *flag;

    f32x16 acc[2][2];
#pragma unroll
    for (int i = 0; i < 2; i++)
#pragma unroll
        for (int j = 0; j < 2; j++)
#pragma unroll
            for (int r = 0; r < 16; r++) acc[i][j][r] = 0.f;

    auto stage = [&](int bufi, int k) {
#pragma unroll
        for (int t = 0; t < 2; t++) {
            const int r = wave * 32 + t * 16;
            gload_lds16(A + (size_t)(m0 + r + srow) * Kd + k + scol,
                        &As[bufi][r * BK]);
            gload_lds16(B + (size_t)(n0 + r + srow) * Kd + k + scol,
                        &Bs[bufi][r * BK]);
        }
    };

    stage(0, 0);
    stage(1, BK);
    int cur = 0, pre = 2;
    for (int k0 = 0; k0 < Kd; k0 += BK) {
        stage(pre, (k0 + 2 * BK) & (Kd - 1));   // wraps at tail: never read
        asm volatile("s_waitcnt vmcnt(8)" ::: "memory");  // tile cur complete
        __builtin_amdgcn_s_barrier();
        __builtin_amdgcn_sched_barrier(0);

        bf16x8 a[2][2], b[2][2];
#pragma unroll
        for (int i = 0; i < 2; i++)
#pragma unroll
            for (int s = 0; s < 2; s++) {
                a[i][s] = *(const bf16x8*)
                    (&As[cur][(wm + i * 32 + l31) * BK + (((s << 1) | hi) ^ xr) * 8]);
                b[i][s] = *(const bf16x8*)
                    (&Bs[cur][(wn + i * 32 + l31) * BK + (((s << 1) | hi) ^ xr) * 8]);
            }
#pragma unroll
        for (int s = 0; s < 2; s++)
#pragma unroll
            for (int i = 0; i < 2; i++)
#pragma unroll
                for (int j = 0; j < 2; j++)
                    acc[i][j] = MFMA32(a[i][s], b[j][s], acc[i][j]);

        asm volatile("s_waitcnt lgkmcnt(0)" ::: "memory");
        __builtin_amdgcn_sched_barrier(0);
        __builtin_amdgcn_s_barrier();
        cur = (cur == 2) ? 0 : cur + 1;
        pre = (pre == 2) ? 0 : pre + 1;
    }

    if (mode == 1) {
        // Vt: C[col][row]; rows g*8+4*hi+0..3 consecutive -> one 8B store.
#pragma unroll
        for (int j = 0; j < 2; j++) {
            const int col = n0 + wn + j * 32 + l31;
            const float bv = bf2f(bias[col]);
#pragma unroll
            for (int i = 0; i < 2; i++) {
#pragma unroll
                for (int g = 0; g < 4; g++) {
                    const int row = m0 + wm + i * 32 + g * 8 + 4 * hi;
                    const float v0 = (acc[i][j][g * 4 + 0] + bv) * scale;
                    const float v1 = (acc[i][j][g * 4 + 1] + bv) * scale;
                    const float v2 = (acc[i][j][g * 4 + 2] + bv) * scale;
                    const float v3 = (acc[i][j][g * 4 + 3] + bv) * scale;
                    i32x2 dd;
                    dd[0] = cvtpk_bf16(v0, v1);
                    dd[1] = cvtpk_bf16(v2, v3);
                    *(i32x2*)((short*)C + (size_t)col * M + row) = dd;
                }
            }
        }
    } else {
#pragma unroll
        for (int j = 0; j < 2; j++) {
            const int col = n0 + wn + j * 32 + l31;
            const float bv = bf2f(bias[col]);
#pragma unroll
            for (int i = 0; i < 2; i++) {
#pragma unroll
                for (int r = 0; r < 16; r++) {
                    const int row = m0 + wm + i * 32 + (r & 3) + 8 * (r >> 2) + 4 * hi;
                    const float v = (acc[i][j][r] + bv) * scale;
                    if (mode == 0) ((short*)C)[(size_t)row * N + col] = f2bf(v);
                    else {
                        if (fl) ((short*)C)[(size_t)row * N + col] = f2bf(v);
                        else    ((float*)C)[(size_t)row * N + col] = v;
                    }
                }
            }
        }
    }
}

// ---------------------------------------------------------------------------
// Flash attention R13 (unchanged, 95us / MfmaUtil 40% / conflicts 0):
// 32x32 swapped-operand structure; both-sides XOR bank fix; ones-MFMA
// row-sum (l_acc[r] = l[qrow(r)] in-lane); gload_lds dbuf + vmcnt(4).
// S^T = mfma(K, Q): lane holds P[q=lane&31][kv subset] lane-locally.
// Aout may alias Q: each wave reads only the 32 Q rows it alone writes.
// ---------------------------------------------------------------------------
__global__ __launch_bounds__(256) void attn_kernel(
    const short* Q, const short* __restrict__ K,
    const short* __restrict__ Vt, short* Aout)
{
    // [buf][0]=K tile [kv 0..63][64 c], [buf][1]=V tile [d 0..63][64 kv]
    __shared__ __align__(16) short lds[2][2][64][64];   // 32 KiB

    const int tid  = threadIdx.x;
    const int lane = tid & 63;
    const int wave = tid >> 6;
    const int l31  = lane & 31;
    const int hi   = lane >> 5;
    const int xr   = (l31 & 7) ^ ((l31 >> 3) & 3);   // read-side XOR

    const int qt = blockIdx.x;
    const int bh = blockIdx.y;
    const int b  = bh >> 4, h = bh & 15;
    const int q0 = b * 2048 + qt * 128 + wave * 32;
    const int c0 = h * 64;

    // staging geometry: lane l -> row r0+(l>>3), LDS chunk l&7;
    // source chunk = (l&7) ^ (l>>3) ^ t  (t = (r0>>3)&3 of the 8-row group)
    const int sr  = lane >> 3;
    const int scb = (lane & 7) ^ sr;
    const int sarr = wave >> 1;                // waves 0,1 -> K; 2,3 -> V

    const short* Kb = K  + (size_t)(b * 2048) * 1024 + c0;
    const short* Vb = Vt + (size_t)c0 * 8192 + b * 2048;

    // Q as B-fragments: lane holds Q[q=l31][c = slot*16 + hi*8 + 0..7]
    bf16x8 qf[4];
#pragma unroll
    for (int slot = 0; slot < 4; slot++)
        qf[slot] = *(const bf16x8*)(Q + (size_t)(q0 + l31) * 1024 + c0 + slot * 16 + hi * 8);

    auto stage = [&](int bufi, int kt) {
#pragma unroll
        for (int t = 0; t < 4; t++) {
            const int r0 = ((wave & 1) * 4 + t) * 8;
            const int sc = (scb ^ t) * 8;
            short* dst = &lds[bufi][sarr][r0][0];       // wave-uniform base
            if (sarr == 0)
                gload_lds16(Kb + (size_t)(kt + r0 + sr) * 1024 + sc, dst);
            else
                gload_lds16(Vb + (size_t)(r0 + sr) * 8192 + kt + sc, dst);
        }
    };

    bf16x8 onesf;
#pragma unroll
    for (int j = 0; j < 8; j++) onesf[j] = (short)0x3F80;   // bf16 1.0

    f32x16 o[2], l_acc;
#pragma unroll
    for (int r = 0; r < 16; r++) { o[0][r] = 0.f; o[1][r] = 0.f; l_acc[r] = 0.f; }

    stage(0, 0);
    for (int kt = 0; kt < 2048; kt += 64) {
        const int cur = (kt >> 6) & 1;
        stage(cur ^ 1, (kt + 64) & 2047);   // last iter wraps: harmless re-stage
        asm volatile("s_waitcnt vmcnt(4)" ::: "memory");  // tile cur complete
        __builtin_amdgcn_s_barrier();
        __builtin_amdgcn_sched_barrier(0);

        // S^T[kv][q]: st[blk] covers kv = blk*32 + crow(reg,hi), q = l31
        f32x16 st[2];
#pragma unroll
        for (int blk = 0; blk < 2; blk++) {
#pragma unroll
            for (int r = 0; r < 16; r++) st[blk][r] = 0.f;
#pragma unroll
            for (int slot = 0; slot < 4; slot++) {
                bf16x8 kf = *(const bf16x8*)
                    &lds[cur][0][blk * 32 + l31][(((slot << 1) | hi) ^ xr) * 8];
                st[blk] = MFMA32(kf, qf[slot], st[blk]);
            }
        }

        // exp (log2-domain scores); row-sum via ones-MFMA below
#pragma unroll
        for (int blk = 0; blk < 2; blk++)
#pragma unroll
            for (int r = 0; r < 16; r++)
                st[blk][r] = fexp2(st[blk][r]);

        // P -> A-fragments (cvt_pk + permlane32_swap) fused with PV MFMAs
#pragma unroll
        for (int ks = 0; ks < 4; ks++) {
            const int blk = ks >> 1;
            const int rb  = (ks & 1) * 8;
            int A0 = cvtpk_bf16(st[blk][rb + 0], st[blk][rb + 1]);
            int A1 = cvtpk_bf16(st[blk][rb + 2], st[blk][rb + 3]);
            int B0 = cvtpk_bf16(st[blk][rb + 4], st[blk][rb + 5]);
            int B1 = cvtpk_bf16(st[blk][rb + 6], st[blk][rb + 7]);
            permswap(A0, B0);   // A0 -> dw0 (j0,j1), B0 -> dw2 (j4,j5)
            permswap(A1, B1);   // A1 -> dw1 (j2,j3), B1 -> dw3 (j6,j7)
            i32x4 paw; paw[0] = A0; paw[1] = A1; paw[2] = B0; paw[3] = B1;
            const bf16x8 pf = *(const bf16x8*)&paw;
            l_acc = MFMA32(pf, onesf, l_acc);   // row-sum on matrix pipe
#pragma unroll
            for (int dblk = 0; dblk < 2; dblk++) {
                bf16x8 vf = *(const bf16x8*)
                    &lds[cur][1][dblk * 32 + l31][(((ks << 1) | hi) ^ xr) * 8];
                o[dblk] = MFMA32(pf, vf, o[dblk]);
            }
        }

        asm volatile("s_waitcnt lgkmcnt(0)" ::: "memory");
        __builtin_amdgcn_sched_barrier(0);
        __builtin_amdgcn_s_barrier();
    }

    // l_acc[r] = l[qrow(r)] already in-lane: no cross-lane reduce needed.
#pragma unroll
    for (int r = 0; r < 16; r++) {
        const int qrow = (r & 3) + 8 * (r >> 2) + 4 * hi;
        const float inv = 1.f / l_acc[r];
#pragma unroll
        for (int dblk = 0; dblk < 2; dblk++)
            Aout[(size_t)(q0 + qrow) * 1024 + c0 + dblk * 32 + l31] =
                f2bf(o[dblk][r] * inv);
    }
}

// ---------------------------------------------------------------------------
extern "C" void kernel_launch(void* const* d_in, const int* in_sizes, int n_in,
                              void* d_out, int out_size, void* d_ws, size_t ws_size,
                              hipStream_t stream)
{
    const size_t MB = (size_t)1024 * 1024;
    char* ws = (char*)d_ws;

    int*   flagp = (int*)ws;                 // [0, 256)
    short* embC  = (short*)(ws + 1 * MB);    // 16 MB [8192][1024]
    short* wC[4] = { (short*)(ws + 17 * MB), (short*)(ws + 19 * MB),
                     (short*)(ws + 21 * MB), (short*)(ws + 23 * MB) };  // 2 MB ea
    short* bC[4] = { (short*)(ws + 25 * MB), (short*)(ws + 25 * MB + 4096),
                     (short*)(ws + 25 * MB + 8192), (short*)(ws + 25 * MB + 12288) };

    short *Qb, *Kb, *Vt, *Ab;
    if (ws_size >= 90 * MB) {
        Qb = (short*)(ws + 26 * MB);
        Kb = (short*)(ws + 42 * MB);
        Vt = (short*)(ws + 58 * MB);
        Ab = (short*)(ws + 74 * MB);
    } else {
        Qb = (short*)(ws + 26 * MB);
        Kb = (short*)d_out;      // dead after attention; final GEMM rewrites
        Vt = (short*)(ws + 42 * MB);
        Ab = Qb;                 // alias: safe per attn_kernel note
    }

    detect_dtype<<<1, 256, 0, stream>>>((const unsigned short*)d_in[0], flagp);

    convert8<<<4096, 256, 0, stream>>>(d_in[0], embC, 1048576, flagp);   // emb
    convert_all<<<2050, 256, 0, stream>>>(
        d_in[1], d_in[3], d_in[5], d_in[7],
        d_in[2], d_in[4], d_in[6], d_in[8],
        wC[0], wC[1], wC[2], wC[3],
        bC[0], bC[1], bC[2], bC[3], flagp);

    dim3 blk(256);
    // Fused QKV; Q scale = log2(e)/8 (log2-domain softmax, see attn header).
    gemm128<<<dim3(512, 1, 3), blk, 0, stream>>>(
        embC, wC[0], wC[1], wC[2], bC[0], bC[1], bC[2],
        Qb, Kb, Vt, 0.18033688011112042f, 1.0f, 1.0f, 0, 0, 1, nullptr);

    attn_kernel<<<dim3(16, 64), blk, 0, stream>>>(Qb, Kb, Vt, Ab);

    gemm128<<<dim3(512, 1, 1), blk, 0, stream>>>(
        Ab, wC[3], nullptr, nullptr, bC[3], nullptr, nullptr,
        d_out, nullptr, nullptr, 1.0f, 0.f, 0.f, 2, 0, 0, flagp);
}

// Round 9
// 321.815 us; speedup vs baseline: 1.0365x; 1.0365x over previous
//
#include <hip/hip_runtime.h>
#include <hip/hip_bf16.h>
#include <math.h>

// bf16 stored as short (raw bits); fp32 accumulate in MFMA.
using bf16x8 = __attribute__((ext_vector_type(8))) short;
using f32x4  = __attribute__((ext_vector_type(4))) float;
using f32x16 = __attribute__((ext_vector_type(16))) float;
using i32x4  = __attribute__((ext_vector_type(4))) int;
using i32x2  = __attribute__((ext_vector_type(2))) int;

#define MFMA_BF16(a, b, c) __builtin_amdgcn_mfma_f32_16x16x32_bf16((a), (b), (c), 0, 0, 0)
#define MFMA32(a, b, c)    __builtin_amdgcn_mfma_f32_32x32x16_bf16((a), (b), (c), 0, 0, 0)

__device__ __forceinline__ float bf2f(short s) {
    union { unsigned u; float f; } v;
    v.u = ((unsigned)(unsigned short)s) << 16;
    return v.f;
}
__device__ __forceinline__ short f2bf(float f) {
    union { float f; unsigned u; } v; v.f = f;
    unsigned r = v.u + 0x7FFF + ((v.u >> 16) & 1);  // round-to-nearest-even
    return (short)(r >> 16);
}
// Native packed f32->bf16 convert (RNE), 1 VALU op for 2 values.
__device__ __forceinline__ int cvtpk_bf16(float lo, float hi) {
    int r;
    asm("v_cvt_pk_bf16_f32 %0, %1, %2" : "=v"(r) : "v"(lo), "v"(hi));
    return r;
}
// v_permlane32_swap_b32: a'[l<32]=a[l], a'[32+i]=b[i]; b'[i]=a[32+i], b'[32+i]=b[32+i].
__device__ __forceinline__ void permswap(int &a, int &b) {
#if __has_builtin(__builtin_amdgcn_permlane32_swap)
    typedef unsigned u32x2v __attribute__((ext_vector_type(2)));
    u32x2v r = __builtin_amdgcn_permlane32_swap((unsigned)a, (unsigned)b, false, false);
    a = (int)r[0]; b = (int)r[1];
#else
    asm volatile("v_permlane32_swap_b32 %0, %1" : "+v"(a), "+v"(b));
#endif
}
// Raw 2^x (v_exp_f32). Q is pre-scaled by log2(e)/8 so this IS exp(score).
__device__ __forceinline__ float fexp2(float x) {
#if __has_builtin(__builtin_amdgcn_exp2f)
    return __builtin_amdgcn_exp2f(x);
#else
    return exp2f(x);
#endif
}

// Async global->LDS DMA, 16B per lane (LDS dest = wave base + lane*16).
__device__ __forceinline__ void gload_lds16(const void* g, void* l) {
    __builtin_amdgcn_global_load_lds(
        (const __attribute__((address_space(1))) void*)g,
        (__attribute__((address_space(3))) void*)l, 16, 0, 0);
}

// ---------------------------------------------------------------------------
// Input dtype detector (proven R3). flag: 1=bf16, 0=fp32.
// ---------------------------------------------------------------------------
__global__ void detect_dtype(const unsigned short* __restrict__ emb, int* flag) {
    __shared__ int tot;
    if (threadIdx.x == 0) tot = 0;
    __syncthreads();
    int c = 0;
    for (int i = 0; i < 64; i++) {
        unsigned short v = emb[2 * (threadIdx.x * 64 + i)];
        unsigned e = (v >> 7) & 0xFF;
        if (v == 0 || v == 0x8000u || (e >= 97 && e <= 137)) c++;
    }
    atomicAdd(&tot, c);
    __syncthreads();
    if (threadIdx.x == 0) *flag = (tot > 8192) ? 1 : 0;
}

__global__ void convert8(const void* __restrict__ src, short* __restrict__ dst,
                         int n8, const int* __restrict__ flag) {
    int i = blockIdx.x * 256 + threadIdx.x;
    if (i >= n8) return;
    if (*flag) {
        ((bf16x8*)dst)[i] = ((const bf16x8*)src)[i];
    } else {
        const float* f = (const float*)src + (size_t)i * 8;
        bf16x8 o;
#pragma unroll
        for (int j = 0; j < 8; j++) o[j] = f2bf(f[j]);
        ((bf16x8*)dst)[i] = o;
    }
}

// All 4 weights (131072 n8 each) + 4 biases (128 n8 each) in ONE launch.
// Grid = 2050 blocks x 256 = 524800 = 4*131072 + 4*128 exactly.
__global__ void convert_all(
    const void* __restrict__ w0, const void* __restrict__ w1,
    const void* __restrict__ w2, const void* __restrict__ w3,
    const void* __restrict__ b0, const void* __restrict__ b1,
    const void* __restrict__ b2, const void* __restrict__ b3,
    short* dw0, short* dw1, short* dw2, short* dw3,
    short* db0, short* db1, short* db2, short* db3,
    const int* __restrict__ flag)
{
    int i = blockIdx.x * 256 + threadIdx.x;
    const void* src; short* dst; int idx;
    if (i < 524288) {
        int w = i >> 17; idx = i & 131071;
        src = (w == 0) ? w0 : (w == 1) ? w1 : (w == 2) ? w2 : w3;
        dst = (w == 0) ? dw0 : (w == 1) ? dw1 : (w == 2) ? dw2 : dw3;
    } else {
        int j = i - 524288; int b = j >> 7; idx = j & 127;
        src = (b == 0) ? b0 : (b == 1) ? b1 : (b == 2) ? b2 : b3;
        dst = (b == 0) ? db0 : (b == 1) ? db1 : (b == 2) ? db2 : db3;
    }
    if (*flag) {
        ((bf16x8*)dst)[idx] = ((const bf16x8*)src)[idx];
    } else {
        const float* f = (const float*)src + (size_t)idx * 8;
        bf16x8 o;
#pragma unroll
        for (int j = 0; j < 8; j++) o[j] = f2bf(f[j]);
        ((bf16x8*)dst)[idx] = o;
    }
}

// ---------------------------------------------------------------------------
// GEMM R15: R14 with the bank swizzle CORRECTED (R14 measured 1.89e7
// conflicts — its c^(r&3) mapping left lanes {l,l+4,...} on identical
// bank slots; see derivation below).
//  - BK=32 rows are 64B = HALF a bank wrap -> bank base depends on r&1 only;
//    8 distinct 16B slots = (r&1) x 4 chunks. Lanes 0..7 must cover all 8:
//    chunk must advance with (l31>>1)&3.
//      store: LDS row r chunk c holds global chunk c^((r>>1)&3)
//             (stage source chunk = (l&3)^((l>>3)&3); base rows mult of 16)
//      read:  chunk = ((s<<1)|hi) ^ ((l31>>1)&3)   (base rows mult of 32)
//    Enumerated: lanes 0..7 -> (0,g),(1,g),(0,g^1),(1,g^1),(0,g^2),(1,g^2),
//    (0,g^3),(1,g^3) = all 8 slots, all 32 banks -> wave64-b128 8-cycle
//    floor, zero extra cycles.
//  - MFMA32 inner: 8 mfma/K-step (vs 16) for the same FLOP. Fragment
//    contract HW-verified by attn: A/B lane&31=m/n, k=(lane>>5)*8+j;
//    C/D col=lane&31, row=(r&3)+8*(r>>2)+4*hi.
//  - Ring-3 LDS, 2 tiles in flight, counted s_waitcnt vmcnt(8).
//  - XCD swizzle (VERIFIED R8: FETCH 135->48 MB): swz=(bid&7)*64+(bid>>3).
// mode: 0 = bf16 natural, 1 = bf16 transposed (Vt), 2 = per *flag dtype.
// ---------------------------------------------------------------------------
__global__ __launch_bounds__(256) void gemm128(
    const short* __restrict__ A,
    const short* __restrict__ B0, const short* __restrict__ B1,
    const short* __restrict__ B2,
    const short* __restrict__ bias0, const short* __restrict__ bias1,
    const short* __restrict__ bias2,
    void* __restrict__ C0, void* __restrict__ C1, void* __restrict__ C2,
    float s0, float s1, float s2,
    int mode0, int mode1, int mode2,
    const int* __restrict__ flag)
{
    constexpr int M = 8192, N = 1024, Kd = 1024, BK = 32;
    __shared__ __align__(16) short As[3][128 * BK];
    __shared__ __align__(16) short Bs[3][128 * BK];

    const int z = blockIdx.z;
    const short* B    = (z == 0) ? B0    : (z == 1) ? B1    : B2;
    const short* bias = (z == 0) ? bias0 : (z == 1) ? bias1 : bias2;
    void*  C     = (z == 0) ? C0 : (z == 1) ? C1 : C2;
    float  scale = (z == 0) ? s0 : (z == 1) ? s1 : s2;
    int    mode  = (z == 0) ? mode0 : (z == 1) ? mode1 : mode2;

    const int tid  = threadIdx.x;
    const int lane = tid & 63;
    const int wave = tid >> 6;
    const int l31  = lane & 31;
    const int hi   = lane >> 5;

    // XCD-aware bijective swizzle (512 blocks, 8 XCDs; XCD = bid%8).
    const int bid = blockIdx.x;
    const int swz = ((bid & 7) << 6) | (bid >> 3);
    const int m0 = (swz >> 3) * 128;
    const int n0 = (swz & 7) * 128;
    const int wm = (wave >> 1) * 64;
    const int wn = (wave & 1) * 64;

    // staging: lane l -> row l>>2, LDS chunk l&3; source chunk (l&3)^((l>>3)&3)
    const int srow = lane >> 2;
    const int scol = ((lane & 3) ^ ((lane >> 3) & 3)) * 8;
    // fragment read chunk XOR: (l31>>1)&3  (row base mult of 32)
    const int xr = (l31 >> 1) & 3;

    int fl = 1;
    if (mode == 2) fl = *flag;

    f32x16 acc[2][2];
#pragma unroll
    for (int i = 0; i < 2; i++)
#pragma unroll
        for (int j = 0; j < 2; j++)
#pragma unroll
            for (int r = 0; r < 16; r++) acc[i][j][r] = 0.f;

    auto stage = [&](int bufi, int k) {
#pragma unroll
        for (int t = 0; t < 2; t++) {
            const int r = wave * 32 + t * 16;
            gload_lds16(A + (size_t)(m0 + r + srow) * Kd + k + scol,
                        &As[bufi][r * BK]);
            gload_lds16(B + (size_t)(n0 + r + srow) * Kd + k + scol,
                        &Bs[bufi][r * BK]);
        }
    };

    stage(0, 0);
    stage(1, BK);
    int cur = 0, pre = 2;
    for (int k0 = 0; k0 < Kd; k0 += BK) {
        stage(pre, (k0 + 2 * BK) & (Kd - 1));   // wraps at tail: never read
        asm volatile("s_waitcnt vmcnt(8)" ::: "memory");  // tile cur complete
        __builtin_amdgcn_s_barrier();
        __builtin_amdgcn_sched_barrier(0);

        bf16x8 a[2][2], b[2][2];
#pragma unroll
        for (int i = 0; i < 2; i++)
#pragma unroll
            for (int s = 0; s < 2; s++) {
                a[i][s] = *(const bf16x8*)
                    (&As[cur][(wm + i * 32 + l31) * BK + (((s << 1) | hi) ^ xr) * 8]);
                b[i][s] = *(const bf16x8*)
                    (&Bs[cur][(wn + i * 32 + l31) * BK + (((s << 1) | hi) ^ xr) * 8]);
            }
#pragma unroll
        for (int s = 0; s < 2; s++)
#pragma unroll
            for (int i = 0; i < 2; i++)
#pragma unroll
                for (int j = 0; j < 2; j++)
                    acc[i][j] = MFMA32(a[i][s], b[j][s], acc[i][j]);

        asm volatile("s_waitcnt lgkmcnt(0)" ::: "memory");
        __builtin_amdgcn_sched_barrier(0);
        __builtin_amdgcn_s_barrier();
        cur = (cur == 2) ? 0 : cur + 1;
        pre = (pre == 2) ? 0 : pre + 1;
    }

    if (mode == 1) {
        // Vt: C[col][row]; rows g*8+4*hi+0..3 consecutive -> one 8B store.
#pragma unroll
        for (int j = 0; j < 2; j++) {
            const int col = n0 + wn + j * 32 + l31;
            const float bv = bf2f(bias[col]);
#pragma unroll
            for (int i = 0; i < 2; i++) {
#pragma unroll
                for (int g = 0; g < 4; g++) {
                    const int row = m0 + wm + i * 32 + g * 8 + 4 * hi;
                    const float v0 = (acc[i][j][g * 4 + 0] + bv) * scale;
                    const float v1 = (acc[i][j][g * 4 + 1] + bv) * scale;
                    const float v2 = (acc[i][j][g * 4 + 2] + bv) * scale;
                    const float v3 = (acc[i][j][g * 4 + 3] + bv) * scale;
                    i32x2 dd;
                    dd[0] = cvtpk_bf16(v0, v1);
                    dd[1] = cvtpk_bf16(v2, v3);
                    *(i32x2*)((short*)C + (size_t)col * M + row) = dd;
                }
            }
        }
    } else {
#pragma unroll
        for (int j = 0; j < 2; j++) {
            const int col = n0 + wn + j * 32 + l31;
            const float bv = bf2f(bias[col]);
#pragma unroll
            for (int i = 0; i < 2; i++) {
#pragma unroll
                for (int r = 0; r < 16; r++) {
                    const int row = m0 + wm + i * 32 + (r & 3) + 8 * (r >> 2) + 4 * hi;
                    const float v = (acc[i][j][r] + bv) * scale;
                    if (mode == 0) ((short*)C)[(size_t)row * N + col] = f2bf(v);
                    else {
                        if (fl) ((short*)C)[(size_t)row * N + col] = f2bf(v);
                        else    ((float*)C)[(size_t)row * N + col] = v;
                    }
                }
            }
        }
    }
}

// ---------------------------------------------------------------------------
// Flash attention R13 (unchanged, 95us / MfmaUtil 40% / conflicts 0):
// 32x32 swapped-operand structure; both-sides XOR bank fix; ones-MFMA
// row-sum (l_acc[r] = l[qrow(r)] in-lane); gload_lds dbuf + vmcnt(4).
// S^T = mfma(K, Q): lane holds P[q=lane&31][kv subset] lane-locally.
// Aout may alias Q: each wave reads only the 32 Q rows it alone writes.
// ---------------------------------------------------------------------------
__global__ __launch_bounds__(256) void attn_kernel(
    const short* Q, const short* __restrict__ K,
    const short* __restrict__ Vt, short* Aout)
{
    // [buf][0]=K tile [kv 0..63][64 c], [buf][1]=V tile [d 0..63][64 kv]
    __shared__ __align__(16) short lds[2][2][64][64];   // 32 KiB

    const int tid  = threadIdx.x;
    const int lane = tid & 63;
    const int wave = tid >> 6;
    const int l31  = lane & 31;
    const int hi   = lane >> 5;
    const int xr   = (l31 & 7) ^ ((l31 >> 3) & 3);   // read-side XOR

    const int qt = blockIdx.x;
    const int bh = blockIdx.y;
    const int b  = bh >> 4, h = bh & 15;
    const int q0 = b * 2048 + qt * 128 + wave * 32;
    const int c0 = h * 64;

    // staging geometry: lane l -> row r0+(l>>3), LDS chunk l&7;
    // source chunk = (l&7) ^ (l>>3) ^ t  (t = (r0>>3)&3 of the 8-row group)
    const int sr  = lane >> 3;
    const int scb = (lane & 7) ^ sr;
    const int sarr = wave >> 1;                // waves 0,1 -> K; 2,3 -> V

    const short* Kb = K  + (size_t)(b * 2048) * 1024 + c0;
    const short* Vb = Vt + (size_t)c0 * 8192 + b * 2048;

    // Q as B-fragments: lane holds Q[q=l31][c = slot*16 + hi*8 + 0..7]
    bf16x8 qf[4];
#pragma unroll
    for (int slot = 0; slot < 4; slot++)
        qf[slot] = *(const bf16x8*)(Q + (size_t)(q0 + l31) * 1024 + c0 + slot * 16 + hi * 8);

    auto stage = [&](int bufi, int kt) {
#pragma unroll
        for (int t = 0; t < 4; t++) {
            const int r0 = ((wave & 1) * 4 + t) * 8;
            const int sc = (scb ^ t) * 8;
            short* dst = &lds[bufi][sarr][r0][0];       // wave-uniform base
            if (sarr == 0)
                gload_lds16(Kb + (size_t)(kt + r0 + sr) * 1024 + sc, dst);
            else
                gload_lds16(Vb + (size_t)(r0 + sr) * 8192 + kt + sc, dst);
        }
    };

    bf16x8 onesf;
#pragma unroll
    for (int j = 0; j < 8; j++) onesf[j] = (short)0x3F80;   // bf16 1.0

    f32x16 o[2], l_acc;
#pragma unroll
    for (int r = 0; r < 16; r++) { o[0][r] = 0.f; o[1][r] = 0.f; l_acc[r] = 0.f; }

    stage(0, 0);
    for (int kt = 0; kt < 2048; kt += 64) {
        const int cur = (kt >> 6) & 1;
        stage(cur ^ 1, (kt + 64) & 2047);   // last iter wraps: harmless re-stage
        asm volatile("s_waitcnt vmcnt(4)" ::: "memory");  // tile cur complete
        __builtin_amdgcn_s_barrier();
        __builtin_amdgcn_sched_barrier(0);

        // S^T[kv][q]: st[blk] covers kv = blk*32 + crow(reg,hi), q = l31
        f32x16 st[2];
#pragma unroll
        for (int blk = 0; blk < 2; blk++) {
#pragma unroll
            for (int r = 0; r < 16; r++) st[blk][r] = 0.f;
#pragma unroll
            for (int slot = 0; slot < 4; slot++) {
                bf16x8 kf = *(const bf16x8*)
                    &lds[cur][0][blk * 32 + l31][(((slot << 1) | hi) ^ xr) * 8];
                st[blk] = MFMA32(kf, qf[slot], st[blk]);
            }
        }

        // exp (log2-domain scores); row-sum via ones-MFMA below
#pragma unroll
        for (int blk = 0; blk < 2; blk++)
#pragma unroll
            for (int r = 0; r < 16; r++)
                st[blk][r] = fexp2(st[blk][r]);

        // P -> A-fragments (cvt_pk + permlane32_swap) fused with PV MFMAs
#pragma unroll
        for (int ks = 0; ks < 4; ks++) {
            const int blk = ks >> 1;
            const int rb  = (ks & 1) * 8;
            int A0 = cvtpk_bf16(st[blk][rb + 0], st[blk][rb + 1]);
            int A1 = cvtpk_bf16(st[blk][rb + 2], st[blk][rb + 3]);
            int B0 = cvtpk_bf16(st[blk][rb + 4], st[blk][rb + 5]);
            int B1 = cvtpk_bf16(st[blk][rb + 6], st[blk][rb + 7]);
            permswap(A0, B0);   // A0 -> dw0 (j0,j1), B0 -> dw2 (j4,j5)
            permswap(A1, B1);   // A1 -> dw1 (j2,j3), B1 -> dw3 (j6,j7)
            i32x4 paw; paw[0] = A0; paw[1] = A1; paw[2] = B0; paw[3] = B1;
            const bf16x8 pf = *(const bf16x8*)&paw;
            l_acc = MFMA32(pf, onesf, l_acc);   // row-sum on matrix pipe
#pragma unroll
            for (int dblk = 0; dblk < 2; dblk++) {
                bf16x8 vf = *(const bf16x8*)
                    &lds[cur][1][dblk * 32 + l31][(((ks << 1) | hi) ^ xr) * 8];
                o[dblk] = MFMA32(pf, vf, o[dblk]);
            }
        }

        asm volatile("s_waitcnt lgkmcnt(0)" ::: "memory");
        __builtin_amdgcn_sched_barrier(0);
        __builtin_amdgcn_s_barrier();
    }

    // l_acc[r] = l[qrow(r)] already in-lane: no cross-lane reduce needed.
#pragma unroll
    for (int r = 0; r < 16; r++) {
        const int qrow = (r & 3) + 8 * (r >> 2) + 4 * hi;
        const float inv = 1.f / l_acc[r];
#pragma unroll
        for (int dblk = 0; dblk < 2; dblk++)
            Aout[(size_t)(q0 + qrow) * 1024 + c0 + dblk * 32 + l31] =
                f2bf(o[dblk][r] * inv);
    }
}

// ---------------------------------------------------------------------------
extern "C" void kernel_launch(void* const* d_in, const int* in_sizes, int n_in,
                              void* d_out, int out_size, void* d_ws, size_t ws_size,
                              hipStream_t stream)
{
    const size_t MB = (size_t)1024 * 1024;
    char* ws = (char*)d_ws;

    int*   flagp = (int*)ws;                 // [0, 256)
    short* embC  = (short*)(ws + 1 * MB);    // 16 MB [8192][1024]
    short* wC[4] = { (short*)(ws + 17 * MB), (short*)(ws + 19 * MB),
                     (short*)(ws + 21 * MB), (short*)(ws + 23 * MB) };  // 2 MB ea
    short* bC[4] = { (short*)(ws + 25 * MB), (short*)(ws + 25 * MB + 4096),
                     (short*)(ws + 25 * MB + 8192), (short*)(ws + 25 * MB + 12288) };

    short *Qb, *Kb, *Vt, *Ab;
    if (ws_size >= 90 * MB) {
        Qb = (short*)(ws + 26 * MB);
        Kb = (short*)(ws + 42 * MB);
        Vt = (short*)(ws + 58 * MB);
        Ab = (short*)(ws + 74 * MB);
    } else {
        Qb = (short*)(ws + 26 * MB);
        Kb = (short*)d_out;      // dead after attention; final GEMM rewrites
        Vt = (short*)(ws + 42 * MB);
        Ab = Qb;                 // alias: safe per attn_kernel note
    }

    detect_dtype<<<1, 256, 0, stream>>>((const unsigned short*)d_in[0], flagp);

    convert8<<<4096, 256, 0, stream>>>(d_in[0], embC, 1048576, flagp);   // emb
    convert_all<<<2050, 256, 0, stream>>>(
        d_in[1], d_in[3], d_in[5], d_in[7],
        d_in[2], d_in[4], d_in[6], d_in[8],
        wC[0], wC[1], wC[2], wC[3],
        bC[0], bC[1], bC[2], bC[3], flagp);

    dim3 blk(256);
    // Fused QKV; Q scale = log2(e)/8 (log2-domain softmax, see attn header).
    gemm128<<<dim3(512, 1, 3), blk, 0, stream>>>(
        embC, wC[0], wC[1], wC[2], bC[0], bC[1], bC[2],
        Qb, Kb, Vt, 0.18033688011112042f, 1.0f, 1.0f, 0, 0, 1, nullptr);

    attn_kernel<<<dim3(16, 64), blk, 0, stream>>>(Qb, Kb, Vt, Ab);

    gemm128<<<dim3(512, 1, 1), blk, 0, stream>>>(
        Ab, wC[3], nullptr, nullptr, bC[3], nullptr, nullptr,
        d_out, nullptr, nullptr, 1.0f, 0.f, 0.f, 2, 0, 0, flagp);
}

// Round 10
// 299.999 us; speedup vs baseline: 1.1118x; 1.0727x over previous
//
#include <hip/hip_runtime.h>
#include <hip/hip_bf16.h>
#include <math.h>

// bf16 stored as short (raw bits); fp32 accumulate in MFMA.
using bf16x8 = __attribute__((ext_vector_type(8))) short;
using f32x4  = __attribute__((ext_vector_type(4))) float;
using f32x16 = __attribute__((ext_vector_type(16))) float;
using i32x4  = __attribute__((ext_vector_type(4))) int;
using i32x2  = __attribute__((ext_vector_type(2))) int;

#define MFMA32(a, b, c) __builtin_amdgcn_mfma_f32_32x32x16_bf16((a), (b), (c), 0, 0, 0)

__device__ __forceinline__ float bf2f(short s) {
    union { unsigned u; float f; } v;
    v.u = ((unsigned)(unsigned short)s) << 16;
    return v.f;
}
__device__ __forceinline__ short f2bf(float f) {
    union { float f; unsigned u; } v; v.f = f;
    unsigned r = v.u + 0x7FFF + ((v.u >> 16) & 1);  // round-to-nearest-even
    return (short)(r >> 16);
}
// Native packed f32->bf16 convert (RNE), 1 VALU op for 2 values.
__device__ __forceinline__ int cvtpk_bf16(float lo, float hi) {
    int r;
    asm("v_cvt_pk_bf16_f32 %0, %1, %2" : "=v"(r) : "v"(lo), "v"(hi));
    return r;
}
// v_permlane32_swap_b32: a'[l<32]=a[l], a'[32+i]=b[i]; b'[i]=a[32+i], b'[32+i]=b[32+i].
__device__ __forceinline__ void permswap(int &a, int &b) {
#if __has_builtin(__builtin_amdgcn_permlane32_swap)
    typedef unsigned u32x2v __attribute__((ext_vector_type(2)));
    u32x2v r = __builtin_amdgcn_permlane32_swap((unsigned)a, (unsigned)b, false, false);
    a = (int)r[0]; b = (int)r[1];
#else
    asm volatile("v_permlane32_swap_b32 %0, %1" : "+v"(a), "+v"(b));
#endif
}
// Raw 2^x (v_exp_f32). Q is pre-scaled by log2(e)/8 so this IS exp(score).
__device__ __forceinline__ float fexp2(float x) {
#if __has_builtin(__builtin_amdgcn_exp2f)
    return __builtin_amdgcn_exp2f(x);
#else
    return exp2f(x);
#endif
}

// Async global->LDS DMA, 16B per lane (LDS dest = wave base + lane*16).
__device__ __forceinline__ void gload_lds16(const void* g, void* l) {
    __builtin_amdgcn_global_load_lds(
        (const __attribute__((address_space(1))) void*)g,
        (__attribute__((address_space(3))) void*)l, 16, 0, 0);
}

// ---------------------------------------------------------------------------
// Input dtype detector (proven R3). flag: 1=bf16, 0=fp32.
// ---------------------------------------------------------------------------
__global__ void detect_dtype(const unsigned short* __restrict__ emb, int* flag) {
    __shared__ int tot;
    if (threadIdx.x == 0) tot = 0;
    __syncthreads();
    int c = 0;
    for (int i = 0; i < 64; i++) {
        unsigned short v = emb[2 * (threadIdx.x * 64 + i)];
        unsigned e = (v >> 7) & 0xFF;
        if (v == 0 || v == 0x8000u || (e >= 97 && e <= 137)) c++;
    }
    atomicAdd(&tot, c);
    __syncthreads();
    if (threadIdx.x == 0) *flag = (tot > 8192) ? 1 : 0;
}

__global__ void convert8(const void* __restrict__ src, short* __restrict__ dst,
                         int n8, const int* __restrict__ flag) {
    int i = blockIdx.x * 256 + threadIdx.x;
    if (i >= n8) return;
    if (*flag) {
        ((bf16x8*)dst)[i] = ((const bf16x8*)src)[i];
    } else {
        const float* f = (const float*)src + (size_t)i * 8;
        bf16x8 o;
#pragma unroll
        for (int j = 0; j < 8; j++) o[j] = f2bf(f[j]);
        ((bf16x8*)dst)[i] = o;
    }
}

// All 4 weights (131072 n8 each) + 4 biases (128 n8 each) in ONE launch.
// Grid = 2050 blocks x 256 = 524800 = 4*131072 + 4*128 exactly.
__global__ void convert_all(
    const void* __restrict__ w0, const void* __restrict__ w1,
    const void* __restrict__ w2, const void* __restrict__ w3,
    const void* __restrict__ b0, const void* __restrict__ b1,
    const void* __restrict__ b2, const void* __restrict__ b3,
    short* dw0, short* dw1, short* dw2, short* dw3,
    short* db0, short* db1, short* db2, short* db3,
    const int* __restrict__ flag)
{
    int i = blockIdx.x * 256 + threadIdx.x;
    const void* src; short* dst; int idx;
    if (i < 524288) {
        int w = i >> 17; idx = i & 131071;
        src = (w == 0) ? w0 : (w == 1) ? w1 : (w == 2) ? w2 : w3;
        dst = (w == 0) ? dw0 : (w == 1) ? dw1 : (w == 2) ? dw2 : dw3;
    } else {
        int j = i - 524288; int b = j >> 7; idx = j & 127;
        src = (b == 0) ? b0 : (b == 1) ? b1 : (b == 2) ? b2 : b3;
        dst = (b == 0) ? db0 : (b == 1) ? db1 : (b == 2) ? db2 : db3;
    }
    if (*flag) {
        ((bf16x8*)dst)[idx] = ((const bf16x8*)src)[idx];
    } else {
        const float* f = (const float*)src + (size_t)idx * 8;
        bf16x8 o;
#pragma unroll
        for (int j = 0; j < 8; j++) o[j] = f2bf(f[j]);
        ((bf16x8*)dst)[idx] = o;
    }
}

// ---------------------------------------------------------------------------
// GEMM R16: 256x128 tile, BK=64, 512 threads (8 waves, 4Mx2N, 64x64/wave).
// The 128x128 2-barrier structure plateaued at ~570 TF (R15, conflicts=0):
// this tile halves staging-bytes/FLOP and barrier count (16 vs 32 pairs for
// K=1024), doubling MFMA work per sync point (16 MFMA32/wave/tile).
//  - Bank swizzle: rows are 64 shorts = 128B = FULL bank wrap -> identical
//    geometry to attn's measured-zero-conflict LDS. Reuse verbatim:
//      store: LDS row r chunk c holds global chunk c^(r&7)^((r>>3)&3)
//      read:  chunk = ((ks<<1)|hi) ^ (l31&7) ^ ((l31>>3)&3)
//    staging source XOR: A call t -> t; B call t -> (2*wave+t)&3.
//  - Double buffer + counted s_waitcnt vmcnt(6) (6 DMA/thread/tile) + raw
//    barriers: next tile's loads stay in flight across the barrier.
//  - MFMA32 fragment contract HW-verified (attn + R15 pass): first operand
//    from A-LDS (lane&31 = M-row), second from B-LDS (lane&31 = N-row);
//    C/D: col(N)=lane&31, row(M)=(r&3)+8*(r>>2)+4*hi.
//  - XCD swizzle (verified R8: FETCH 135->48 MB), 256 blocks/z:
//    swz=(bid&7)*32+(bid>>3); each XCD owns 4 m-panels (2 MB, L2-resident).
// mode: 0 = bf16 natural, 1 = bf16 transposed (Vt), 2 = per *flag dtype.
// ---------------------------------------------------------------------------
__global__ __launch_bounds__(512) void gemm256(
    const short* __restrict__ A,
    const short* __restrict__ B0, const short* __restrict__ B1,
    const short* __restrict__ B2,
    const short* __restrict__ bias0, const short* __restrict__ bias1,
    const short* __restrict__ bias2,
    void* __restrict__ C0, void* __restrict__ C1, void* __restrict__ C2,
    float s0, float s1, float s2,
    int mode0, int mode1, int mode2,
    const int* __restrict__ flag)
{
    constexpr int M = 8192, N = 1024, Kd = 1024, BK = 64;
    __shared__ __align__(16) short Al[2][256][BK];   // 64 KB
    __shared__ __align__(16) short Bl[2][128][BK];   // 32 KB

    const int z = blockIdx.z;
    const short* B    = (z == 0) ? B0    : (z == 1) ? B1    : B2;
    const short* bias = (z == 0) ? bias0 : (z == 1) ? bias1 : bias2;
    void*  C     = (z == 0) ? C0 : (z == 1) ? C1 : C2;
    float  scale = (z == 0) ? s0 : (z == 1) ? s1 : s2;
    int    mode  = (z == 0) ? mode0 : (z == 1) ? mode1 : mode2;

    const int tid  = threadIdx.x;
    const int lane = tid & 63;
    const int wave = tid >> 6;          // 0..7
    const int l31  = lane & 31;
    const int hi   = lane >> 5;
    const int xr   = (l31 & 7) ^ ((l31 >> 3) & 3);   // read-side XOR (attn-proven)

    // XCD-aware bijective swizzle (256 blocks/z, 8 XCDs; XCD = bid%8).
    const int bid = blockIdx.x;
    const int swz = ((bid & 7) << 5) | (bid >> 3);
    const int m0 = (swz >> 3) * 256;
    const int n0 = (swz & 7) * 128;
    const int wm = (wave >> 1) * 64;    // 4 M-groups
    const int wn = (wave & 1) * 64;     // 2 N-groups

    // staging: lane l -> row r0+(l>>3), LDS chunk l&7
    const int sr  = lane >> 3;
    const int scb = (lane & 7) ^ sr;

    int fl = 1;
    if (mode == 2) fl = *flag;

    f32x16 acc[2][2];
#pragma unroll
    for (int i = 0; i < 2; i++)
#pragma unroll
        for (int j = 0; j < 2; j++)
#pragma unroll
            for (int r = 0; r < 16; r++) acc[i][j][r] = 0.f;

    // 6 DMA/thread/tile: A 4 calls (32 rows/wave), B 2 calls (16 rows/wave).
    auto stage = [&](int bufi, int k) {
#pragma unroll
        for (int t = 0; t < 4; t++) {
            const int r0 = wave * 32 + t * 8;           // (r0>>3)&3 == t
            gload_lds16(A + (size_t)(m0 + r0 + sr) * Kd + k + ((scb ^ t) & 7) * 8,
                        &Al[bufi][r0][0]);
        }
#pragma unroll
        for (int t = 0; t < 2; t++) {
            const int r0 = wave * 16 + t * 8;           // (r0>>3)&3 == (2w+t)&3
            const int tb = (wave * 2 + t) & 3;
            gload_lds16(B + (size_t)(n0 + r0 + sr) * Kd + k + ((scb ^ tb) & 7) * 8,
                        &Bl[bufi][r0][0]);
        }
    };

    stage(0, 0);
    for (int k0 = 0; k0 < Kd; k0 += BK) {
        const int cur = (k0 >> 6) & 1;
        stage(cur ^ 1, (k0 + BK) & (Kd - 1));   // wraps at tail: never read
        asm volatile("s_waitcnt vmcnt(6)" ::: "memory");  // tile cur complete
        __builtin_amdgcn_s_barrier();
        __builtin_amdgcn_sched_barrier(0);

#pragma unroll
        for (int ks = 0; ks < 4; ks++) {
            const int rc = (((ks << 1) | hi) ^ xr) * 8;
            bf16x8 a0 = *(const bf16x8*)(&Al[cur][wm + l31][rc]);
            bf16x8 a1 = *(const bf16x8*)(&Al[cur][wm + 32 + l31][rc]);
            bf16x8 b0 = *(const bf16x8*)(&Bl[cur][wn + l31][rc]);
            bf16x8 b1 = *(const bf16x8*)(&Bl[cur][wn + 32 + l31][rc]);
            acc[0][0] = MFMA32(a0, b0, acc[0][0]);
            acc[0][1] = MFMA32(a0, b1, acc[0][1]);
            acc[1][0] = MFMA32(a1, b0, acc[1][0]);
            acc[1][1] = MFMA32(a1, b1, acc[1][1]);
        }

        asm volatile("s_waitcnt lgkmcnt(0)" ::: "memory");
        __builtin_amdgcn_sched_barrier(0);
        __builtin_amdgcn_s_barrier();
    }

    if (mode == 1) {
        // Vt: C[col][row]; rows g*8+4*hi+0..3 consecutive -> one 8B store.
#pragma unroll
        for (int j = 0; j < 2; j++) {
            const int col = n0 + wn + j * 32 + l31;
            const float bv = bf2f(bias[col]);
#pragma unroll
            for (int i = 0; i < 2; i++) {
#pragma unroll
                for (int g = 0; g < 4; g++) {
                    const int row = m0 + wm + i * 32 + g * 8 + 4 * hi;
                    const float v0 = (acc[i][j][g * 4 + 0] + bv) * scale;
                    const float v1 = (acc[i][j][g * 4 + 1] + bv) * scale;
                    const float v2 = (acc[i][j][g * 4 + 2] + bv) * scale;
                    const float v3 = (acc[i][j][g * 4 + 3] + bv) * scale;
                    i32x2 dd;
                    dd[0] = cvtpk_bf16(v0, v1);
                    dd[1] = cvtpk_bf16(v2, v3);
                    *(i32x2*)((short*)C + (size_t)col * M + row) = dd;
                }
            }
        }
    } else {
#pragma unroll
        for (int j = 0; j < 2; j++) {
            const int col = n0 + wn + j * 32 + l31;
            const float bv = bf2f(bias[col]);
#pragma unroll
            for (int i = 0; i < 2; i++) {
#pragma unroll
                for (int r = 0; r < 16; r++) {
                    const int row = m0 + wm + i * 32 + (r & 3) + 8 * (r >> 2) + 4 * hi;
                    const float v = (acc[i][j][r] + bv) * scale;
                    if (mode == 0) ((short*)C)[(size_t)row * N + col] = f2bf(v);
                    else {
                        if (fl) ((short*)C)[(size_t)row * N + col] = f2bf(v);
                        else    ((float*)C)[(size_t)row * N + col] = v;
                    }
                }
            }
        }
    }
}

// ---------------------------------------------------------------------------
// Flash attention R13 (unchanged, 95us / MfmaUtil 40% / conflicts 0):
// 32x32 swapped-operand structure; both-sides XOR bank fix; ones-MFMA
// row-sum (l_acc[r] = l[qrow(r)] in-lane); gload_lds dbuf + vmcnt(4).
// S^T = mfma(K, Q): lane holds P[q=lane&31][kv subset] lane-locally.
// Aout may alias Q: each wave reads only the 32 Q rows it alone writes.
// ---------------------------------------------------------------------------
__global__ __launch_bounds__(256) void attn_kernel(
    const short* Q, const short* __restrict__ K,
    const short* __restrict__ Vt, short* Aout)
{
    // [buf][0]=K tile [kv 0..63][64 c], [buf][1]=V tile [d 0..63][64 kv]
    __shared__ __align__(16) short lds[2][2][64][64];   // 32 KiB

    const int tid  = threadIdx.x;
    const int lane = tid & 63;
    const int wave = tid >> 6;
    const int l31  = lane & 31;
    const int hi   = lane >> 5;
    const int xr   = (l31 & 7) ^ ((l31 >> 3) & 3);   // read-side XOR

    const int qt = blockIdx.x;
    const int bh = blockIdx.y;
    const int b  = bh >> 4, h = bh & 15;
    const int q0 = b * 2048 + qt * 128 + wave * 32;
    const int c0 = h * 64;

    // staging geometry: lane l -> row r0+(l>>3), LDS chunk l&7;
    // source chunk = (l&7) ^ (l>>3) ^ t  (t = (r0>>3)&3 of the 8-row group)
    const int sr  = lane >> 3;
    const int scb = (lane & 7) ^ sr;
    const int sarr = wave >> 1;                // waves 0,1 -> K; 2,3 -> V

    const short* Kb = K  + (size_t)(b * 2048) * 1024 + c0;
    const short* Vb = Vt + (size_t)c0 * 8192 + b * 2048;

    // Q as B-fragments: lane holds Q[q=l31][c = slot*16 + hi*8 + 0..7]
    bf16x8 qf[4];
#pragma unroll
    for (int slot = 0; slot < 4; slot++)
        qf[slot] = *(const bf16x8*)(Q + (size_t)(q0 + l31) * 1024 + c0 + slot * 16 + hi * 8);

    auto stage = [&](int bufi, int kt) {
#pragma unroll
        for (int t = 0; t < 4; t++) {
            const int r0 = ((wave & 1) * 4 + t) * 8;
            const int sc = (scb ^ t) * 8;
            short* dst = &lds[bufi][sarr][r0][0];       // wave-uniform base
            if (sarr == 0)
                gload_lds16(Kb + (size_t)(kt + r0 + sr) * 1024 + sc, dst);
            else
                gload_lds16(Vb + (size_t)(r0 + sr) * 8192 + kt + sc, dst);
        }
    };

    bf16x8 onesf;
#pragma unroll
    for (int j = 0; j < 8; j++) onesf[j] = (short)0x3F80;   // bf16 1.0

    f32x16 o[2], l_acc;
#pragma unroll
    for (int r = 0; r < 16; r++) { o[0][r] = 0.f; o[1][r] = 0.f; l_acc[r] = 0.f; }

    stage(0, 0);
    for (int kt = 0; kt < 2048; kt += 64) {
        const int cur = (kt >> 6) & 1;
        stage(cur ^ 1, (kt + 64) & 2047);   // last iter wraps: harmless re-stage
        asm volatile("s_waitcnt vmcnt(4)" ::: "memory");  // tile cur complete
        __builtin_amdgcn_s_barrier();
        __builtin_amdgcn_sched_barrier(0);

        // S^T[kv][q]: st[blk] covers kv = blk*32 + crow(reg,hi), q = l31
        f32x16 st[2];
#pragma unroll
        for (int blk = 0; blk < 2; blk++) {
#pragma unroll
            for (int r = 0; r < 16; r++) st[blk][r] = 0.f;
#pragma unroll
            for (int slot = 0; slot < 4; slot++) {
                bf16x8 kf = *(const bf16x8*)
                    &lds[cur][0][blk * 32 + l31][(((slot << 1) | hi) ^ xr) * 8];
                st[blk] = MFMA32(kf, qf[slot], st[blk]);
            }
        }

        // exp (log2-domain scores); row-sum via ones-MFMA below
#pragma unroll
        for (int blk = 0; blk < 2; blk++)
#pragma unroll
            for (int r = 0; r < 16; r++)
                st[blk][r] = fexp2(st[blk][r]);

        // P -> A-fragments (cvt_pk + permlane32_swap) fused with PV MFMAs
#pragma unroll
        for (int ks = 0; ks < 4; ks++) {
            const int blk = ks >> 1;
            const int rb  = (ks & 1) * 8;
            int A0 = cvtpk_bf16(st[blk][rb + 0], st[blk][rb + 1]);
            int A1 = cvtpk_bf16(st[blk][rb + 2], st[blk][rb + 3]);
            int B0 = cvtpk_bf16(st[blk][rb + 4], st[blk][rb + 5]);
            int B1 = cvtpk_bf16(st[blk][rb + 6], st[blk][rb + 7]);
            permswap(A0, B0);   // A0 -> dw0 (j0,j1), B0 -> dw2 (j4,j5)
            permswap(A1, B1);   // A1 -> dw1 (j2,j3), B1 -> dw3 (j6,j7)
            i32x4 paw; paw[0] = A0; paw[1] = A1; paw[2] = B0; paw[3] = B1;
            const bf16x8 pf = *(const bf16x8*)&paw;
            l_acc = MFMA32(pf, onesf, l_acc);   // row-sum on matrix pipe
#pragma unroll
            for (int dblk = 0; dblk < 2; dblk++) {
                bf16x8 vf = *(const bf16x8*)
                    &lds[cur][1][dblk * 32 + l31][(((ks << 1) | hi) ^ xr) * 8];
                o[dblk] = MFMA32(pf, vf, o[dblk]);
            }
        }

        asm volatile("s_waitcnt lgkmcnt(0)" ::: "memory");
        __builtin_amdgcn_sched_barrier(0);
        __builtin_amdgcn_s_barrier();
    }

    // l_acc[r] = l[qrow(r)] already in-lane: no cross-lane reduce needed.
#pragma unroll
    for (int r = 0; r < 16; r++) {
        const int qrow = (r & 3) + 8 * (r >> 2) + 4 * hi;
        const float inv = 1.f / l_acc[r];
#pragma unroll
        for (int dblk = 0; dblk < 2; dblk++)
            Aout[(size_t)(q0 + qrow) * 1024 + c0 + dblk * 32 + l31] =
                f2bf(o[dblk][r] * inv);
    }
}

// ---------------------------------------------------------------------------
extern "C" void kernel_launch(void* const* d_in, const int* in_sizes, int n_in,
                              void* d_out, int out_size, void* d_ws, size_t ws_size,
                              hipStream_t stream)
{
    const size_t MB = (size_t)1024 * 1024;
    char* ws = (char*)d_ws;

    int*   flagp = (int*)ws;                 // [0, 256)
    short* embC  = (short*)(ws + 1 * MB);    // 16 MB [8192][1024]
    short* wC[4] = { (short*)(ws + 17 * MB), (short*)(ws + 19 * MB),
                     (short*)(ws + 21 * MB), (short*)(ws + 23 * MB) };  // 2 MB ea
    short* bC[4] = { (short*)(ws + 25 * MB), (short*)(ws + 25 * MB + 4096),
                     (short*)(ws + 25 * MB + 8192), (short*)(ws + 25 * MB + 12288) };

    short *Qb, *Kb, *Vt, *Ab;
    if (ws_size >= 90 * MB) {
        Qb = (short*)(ws + 26 * MB);
        Kb = (short*)(ws + 42 * MB);
        Vt = (short*)(ws + 58 * MB);
        Ab = (short*)(ws + 74 * MB);
    } else {
        Qb = (short*)(ws + 26 * MB);
        Kb = (short*)d_out;      // dead after attention; final GEMM rewrites
        Vt = (short*)(ws + 42 * MB);
        Ab = Qb;                 // alias: safe per attn_kernel note
    }

    detect_dtype<<<1, 256, 0, stream>>>((const unsigned short*)d_in[0], flagp);

    convert8<<<4096, 256, 0, stream>>>(d_in[0], embC, 1048576, flagp);   // emb
    convert_all<<<2050, 256, 0, stream>>>(
        d_in[1], d_in[3], d_in[5], d_in[7],
        d_in[2], d_in[4], d_in[6], d_in[8],
        wC[0], wC[1], wC[2], wC[3],
        bC[0], bC[1], bC[2], bC[3], flagp);

    dim3 blk(512);
    // Fused QKV; Q scale = log2(e)/8 (log2-domain softmax, see attn header).
    gemm256<<<dim3(256, 1, 3), blk, 0, stream>>>(
        embC, wC[0], wC[1], wC[2], bC[0], bC[1], bC[2],
        Qb, Kb, Vt, 0.18033688011112042f, 1.0f, 1.0f, 0, 0, 1, nullptr);

    attn_kernel<<<dim3(16, 64), dim3(256), 0, stream>>>(Qb, Kb, Vt, Ab);

    gemm256<<<dim3(256, 1, 1), blk, 0, stream>>>(
        Ab, wC[3], nullptr, nullptr, bC[3], nullptr, nullptr,
        d_out, nullptr, nullptr, 1.0f, 0.f, 0.f, 2, 0, 0, flagp);
}

// Round 11
// 296.006 us; speedup vs baseline: 1.1268x; 1.0135x over previous
//
#include <hip/hip_runtime.h>
#include <hip/hip_bf16.h>
#include <math.h>

// bf16 stored as short (raw bits); fp32 accumulate in MFMA.
using bf16x8 = __attribute__((ext_vector_type(8))) short;
using f32x4  = __attribute__((ext_vector_type(4))) float;
using f32x16 = __attribute__((ext_vector_type(16))) float;
using i32x4  = __attribute__((ext_vector_type(4))) int;
using i32x2  = __attribute__((ext_vector_type(2))) int;

#define MFMA32(a, b, c) __builtin_amdgcn_mfma_f32_32x32x16_bf16((a), (b), (c), 0, 0, 0)

__device__ __forceinline__ float bf2f(short s) {
    union { unsigned u; float f; } v;
    v.u = ((unsigned)(unsigned short)s) << 16;
    return v.f;
}
__device__ __forceinline__ short f2bf(float f) {
    union { float f; unsigned u; } v; v.f = f;
    unsigned r = v.u + 0x7FFF + ((v.u >> 16) & 1);  // round-to-nearest-even
    return (short)(r >> 16);
}
// Native packed f32->bf16 convert (RNE), 1 VALU op for 2 values.
__device__ __forceinline__ int cvtpk_bf16(float lo, float hi) {
    int r;
    asm("v_cvt_pk_bf16_f32 %0, %1, %2" : "=v"(r) : "v"(lo), "v"(hi));
    return r;
}
// v_permlane32_swap_b32: a'[l<32]=a[l], a'[32+i]=b[i]; b'[i]=a[32+i], b'[32+i]=b[32+i].
__device__ __forceinline__ void permswap(int &a, int &b) {
#if __has_builtin(__builtin_amdgcn_permlane32_swap)
    typedef unsigned u32x2v __attribute__((ext_vector_type(2)));
    u32x2v r = __builtin_amdgcn_permlane32_swap((unsigned)a, (unsigned)b, false, false);
    a = (int)r[0]; b = (int)r[1];
#else
    asm volatile("v_permlane32_swap_b32 %0, %1" : "+v"(a), "+v"(b));
#endif
}
// Raw 2^x (v_exp_f32). Q is pre-scaled by log2(e)/8 so this IS exp(score).
__device__ __forceinline__ float fexp2(float x) {
#if __has_builtin(__builtin_amdgcn_exp2f)
    return __builtin_amdgcn_exp2f(x);
#else
    return exp2f(x);
#endif
}

// Async global->LDS DMA, 16B per lane (LDS dest = wave base + lane*16).
__device__ __forceinline__ void gload_lds16(const void* g, void* l) {
    __builtin_amdgcn_global_load_lds(
        (const __attribute__((address_space(1))) void*)g,
        (__attribute__((address_space(3))) void*)l, 16, 0, 0);
}

// ---------------------------------------------------------------------------
// preprocess R17: detect + convert8 + convert_all FUSED into one launch
// (was 3 launches; inter-dispatch gaps ~90us total across the pipeline).
// Each block re-derives the dtype flag from a per-block 256-sample vote over
// the first 512 shorts of emb (binomial separation: fp32 low-halves match
// the bf16-exponent pattern at p~0.16 -> E[count]~41/256; genuine bf16 ->
// ~256/256; threshold 128 errs with negligible probability). Block 0 also
// writes the global flag for the out-proj GEMM's mode-2 epilogue.
// Grid: 4096 emb blocks + 2050 weight/bias blocks = 6146 x 256.
// ---------------------------------------------------------------------------
__global__ void preprocess(
    const void* __restrict__ emb, short* __restrict__ embC,
    const void* __restrict__ w0, const void* __restrict__ w1,
    const void* __restrict__ w2, const void* __restrict__ w3,
    const void* __restrict__ b0, const void* __restrict__ b1,
    const void* __restrict__ b2, const void* __restrict__ b3,
    short* dw0, short* dw1, short* dw2, short* dw3,
    short* db0, short* db1, short* db2, short* db3,
    int* flagp)
{
    __shared__ int vote;
    const int tid = threadIdx.x;
    if (tid == 0) vote = 0;
    __syncthreads();
    {
        unsigned short v = ((const unsigned short*)emb)[2 * tid];
        unsigned e = (v >> 7) & 0xFF;
        int c = (v == 0 || v == 0x8000u || (e >= 97 && e <= 137)) ? 1 : 0;
        atomicAdd(&vote, c);
    }
    __syncthreads();
    const int fl = vote > 128;
    if (blockIdx.x == 0 && tid == 0) *flagp = fl;

    const void* src; short* dst; int idx;
    if (blockIdx.x < 4096) {                    // embeddings: 1048576 n8
        src = emb; dst = embC; idx = blockIdx.x * 256 + tid;
    } else {
        int i = (blockIdx.x - 4096) * 256 + tid;
        if (i < 524288) {                       // weights: 4 x 131072 n8
            int w = i >> 17; idx = i & 131071;
            src = (w == 0) ? w0 : (w == 1) ? w1 : (w == 2) ? w2 : w3;
            dst = (w == 0) ? dw0 : (w == 1) ? dw1 : (w == 2) ? dw2 : dw3;
        } else {                                // biases: 4 x 128 n8
            int j = i - 524288; int b = j >> 7; idx = j & 127;
            src = (b == 0) ? b0 : (b == 1) ? b1 : (b == 2) ? b2 : b3;
            dst = (b == 0) ? db0 : (b == 1) ? db1 : (b == 2) ? db2 : db3;
        }
    }
    if (fl) {
        ((bf16x8*)dst)[idx] = ((const bf16x8*)src)[idx];
    } else {
        const float* f = (const float*)src + (size_t)idx * 8;
        bf16x8 o;
#pragma unroll
        for (int j = 0; j < 8; j++) o[j] = f2bf(f[j]);
        ((bf16x8*)dst)[idx] = o;
    }
}

// ---------------------------------------------------------------------------
// GEMM R16 (unchanged; verified R10: total -22us, QKV ~67us ~750 TF):
// 256x128 tile, BK=64, 512 threads (8 waves, 4Mx2N, 64x64/wave).
//  - Bank swizzle: rows 64 shorts = 128B = full bank wrap; attn-proven
//    zero-conflict mapping (store c^(r&7)^((r>>3)&3); read xr XOR).
//  - Double buffer + counted s_waitcnt vmcnt(6) + raw barriers.
//  - XCD swizzle (verified R8: FETCH 135->48 MB).
// mode: 0 = bf16 natural, 1 = bf16 transposed (Vt), 2 = per *flag dtype.
// ---------------------------------------------------------------------------
__global__ __launch_bounds__(512) void gemm256(
    const short* __restrict__ A,
    const short* __restrict__ B0, const short* __restrict__ B1,
    const short* __restrict__ B2,
    const short* __restrict__ bias0, const short* __restrict__ bias1,
    const short* __restrict__ bias2,
    void* __restrict__ C0, void* __restrict__ C1, void* __restrict__ C2,
    float s0, float s1, float s2,
    int mode0, int mode1, int mode2,
    const int* __restrict__ flag)
{
    constexpr int M = 8192, N = 1024, Kd = 1024, BK = 64;
    __shared__ __align__(16) short Al[2][256][BK];   // 64 KB
    __shared__ __align__(16) short Bl[2][128][BK];   // 32 KB

    const int z = blockIdx.z;
    const short* B    = (z == 0) ? B0    : (z == 1) ? B1    : B2;
    const short* bias = (z == 0) ? bias0 : (z == 1) ? bias1 : bias2;
    void*  C     = (z == 0) ? C0 : (z == 1) ? C1 : C2;
    float  scale = (z == 0) ? s0 : (z == 1) ? s1 : s2;
    int    mode  = (z == 0) ? mode0 : (z == 1) ? mode1 : mode2;

    const int tid  = threadIdx.x;
    const int lane = tid & 63;
    const int wave = tid >> 6;          // 0..7
    const int l31  = lane & 31;
    const int hi   = lane >> 5;
    const int xr   = (l31 & 7) ^ ((l31 >> 3) & 3);   // read-side XOR (attn-proven)

    // XCD-aware bijective swizzle (256 blocks/z, 8 XCDs; XCD = bid%8).
    const int bid = blockIdx.x;
    const int swz = ((bid & 7) << 5) | (bid >> 3);
    const int m0 = (swz >> 3) * 256;
    const int n0 = (swz & 7) * 128;
    const int wm = (wave >> 1) * 64;    // 4 M-groups
    const int wn = (wave & 1) * 64;     // 2 N-groups

    // staging: lane l -> row r0+(l>>3), LDS chunk l&7
    const int sr  = lane >> 3;
    const int scb = (lane & 7) ^ sr;

    int fl = 1;
    if (mode == 2) fl = *flag;

    f32x16 acc[2][2];
#pragma unroll
    for (int i = 0; i < 2; i++)
#pragma unroll
        for (int j = 0; j < 2; j++)
#pragma unroll
            for (int r = 0; r < 16; r++) acc[i][j][r] = 0.f;

    // 6 DMA/thread/tile: A 4 calls (32 rows/wave), B 2 calls (16 rows/wave).
    auto stage = [&](int bufi, int k) {
#pragma unroll
        for (int t = 0; t < 4; t++) {
            const int r0 = wave * 32 + t * 8;           // (r0>>3)&3 == t
            gload_lds16(A + (size_t)(m0 + r0 + sr) * Kd + k + ((scb ^ t) & 7) * 8,
                        &Al[bufi][r0][0]);
        }
#pragma unroll
        for (int t = 0; t < 2; t++) {
            const int r0 = wave * 16 + t * 8;           // (r0>>3)&3 == (2w+t)&3
            const int tb = (wave * 2 + t) & 3;
            gload_lds16(B + (size_t)(n0 + r0 + sr) * Kd + k + ((scb ^ tb) & 7) * 8,
                        &Bl[bufi][r0][0]);
        }
    };

    stage(0, 0);
    for (int k0 = 0; k0 < Kd; k0 += BK) {
        const int cur = (k0 >> 6) & 1;
        stage(cur ^ 1, (k0 + BK) & (Kd - 1));   // wraps at tail: never read
        asm volatile("s_waitcnt vmcnt(6)" ::: "memory");  // tile cur complete
        __builtin_amdgcn_s_barrier();
        __builtin_amdgcn_sched_barrier(0);

#pragma unroll
        for (int ks = 0; ks < 4; ks++) {
            const int rc = (((ks << 1) | hi) ^ xr) * 8;
            bf16x8 a0 = *(const bf16x8*)(&Al[cur][wm + l31][rc]);
            bf16x8 a1 = *(const bf16x8*)(&Al[cur][wm + 32 + l31][rc]);
            bf16x8 b0 = *(const bf16x8*)(&Bl[cur][wn + l31][rc]);
            bf16x8 b1 = *(const bf16x8*)(&Bl[cur][wn + 32 + l31][rc]);
            acc[0][0] = MFMA32(a0, b0, acc[0][0]);
            acc[0][1] = MFMA32(a0, b1, acc[0][1]);
            acc[1][0] = MFMA32(a1, b0, acc[1][0]);
            acc[1][1] = MFMA32(a1, b1, acc[1][1]);
        }

        asm volatile("s_waitcnt lgkmcnt(0)" ::: "memory");
        __builtin_amdgcn_sched_barrier(0);
        __builtin_amdgcn_s_barrier();
    }

    if (mode == 1) {
        // Vt: C[col][row]; rows g*8+4*hi+0..3 consecutive -> one 8B store.
#pragma unroll
        for (int j = 0; j < 2; j++) {
            const int col = n0 + wn + j * 32 + l31;
            const float bv = bf2f(bias[col]);
#pragma unroll
            for (int i = 0; i < 2; i++) {
#pragma unroll
                for (int g = 0; g < 4; g++) {
                    const int row = m0 + wm + i * 32 + g * 8 + 4 * hi;
                    const float v0 = (acc[i][j][g * 4 + 0] + bv) * scale;
                    const float v1 = (acc[i][j][g * 4 + 1] + bv) * scale;
                    const float v2 = (acc[i][j][g * 4 + 2] + bv) * scale;
                    const float v3 = (acc[i][j][g * 4 + 3] + bv) * scale;
                    i32x2 dd;
                    dd[0] = cvtpk_bf16(v0, v1);
                    dd[1] = cvtpk_bf16(v2, v3);
                    *(i32x2*)((short*)C + (size_t)col * M + row) = dd;
                }
            }
        }
    } else {
#pragma unroll
        for (int j = 0; j < 2; j++) {
            const int col = n0 + wn + j * 32 + l31;
            const float bv = bf2f(bias[col]);
#pragma unroll
            for (int i = 0; i < 2; i++) {
#pragma unroll
                for (int r = 0; r < 16; r++) {
                    const int row = m0 + wm + i * 32 + (r & 3) + 8 * (r >> 2) + 4 * hi;
                    const float v = (acc[i][j][r] + bv) * scale;
                    if (mode == 0) ((short*)C)[(size_t)row * N + col] = f2bf(v);
                    else {
                        if (fl) ((short*)C)[(size_t)row * N + col] = f2bf(v);
                        else    ((float*)C)[(size_t)row * N + col] = v;
                    }
                }
            }
        }
    }
}

// ---------------------------------------------------------------------------
// Flash attention R17: R13 + zero-C MFMA trick.
//  - st[] was re-zeroed every tile: 32 v_mov/lane/tile (~15% of VALU ops on
//    a 59%-VALUBusy kernel). Now slot-0 MFMA uses a loop-invariant fz zero
//    vector as C (D!=C legal; fz lives untouched in 16 VGPRs). VGPR 84->~100,
//    still clear of spill/occupancy cliffs (limiter is neither VGPR nor LDS).
//  - Everything else unchanged (95us / MfmaUtil 40% / conflicts 0): 32x32
//    swapped-operand; both-sides XOR bank fix; ones-MFMA row-sum; gload_lds
//    dbuf + counted vmcnt(4).
// S^T = mfma(K, Q): lane holds P[q=lane&31][kv subset] lane-locally.
// Aout may alias Q: each wave reads only the 32 Q rows it alone writes.
// ---------------------------------------------------------------------------
__global__ __launch_bounds__(256) void attn_kernel(
    const short* Q, const short* __restrict__ K,
    const short* __restrict__ Vt, short* Aout)
{
    // [buf][0]=K tile [kv 0..63][64 c], [buf][1]=V tile [d 0..63][64 kv]
    __shared__ __align__(16) short lds[2][2][64][64];   // 32 KiB

    const int tid  = threadIdx.x;
    const int lane = tid & 63;
    const int wave = tid >> 6;
    const int l31  = lane & 31;
    const int hi   = lane >> 5;
    const int xr   = (l31 & 7) ^ ((l31 >> 3) & 3);   // read-side XOR

    const int qt = blockIdx.x;
    const int bh = blockIdx.y;
    const int b  = bh >> 4, h = bh & 15;
    const int q0 = b * 2048 + qt * 128 + wave * 32;
    const int c0 = h * 64;

    // staging geometry: lane l -> row r0+(l>>3), LDS chunk l&7;
    // source chunk = (l&7) ^ (l>>3) ^ t  (t = (r0>>3)&3 of the 8-row group)
    const int sr  = lane >> 3;
    const int scb = (lane & 7) ^ sr;
    const int sarr = wave >> 1;                // waves 0,1 -> K; 2,3 -> V

    const short* Kb = K  + (size_t)(b * 2048) * 1024 + c0;
    const short* Vb = Vt + (size_t)c0 * 8192 + b * 2048;

    // Q as B-fragments: lane holds Q[q=l31][c = slot*16 + hi*8 + 0..7]
    bf16x8 qf[4];
#pragma unroll
    for (int slot = 0; slot < 4; slot++)
        qf[slot] = *(const bf16x8*)(Q + (size_t)(q0 + l31) * 1024 + c0 + slot * 16 + hi * 8);

    auto stage = [&](int bufi, int kt) {
#pragma unroll
        for (int t = 0; t < 4; t++) {
            const int r0 = ((wave & 1) * 4 + t) * 8;
            const int sc = (scb ^ t) * 8;
            short* dst = &lds[bufi][sarr][r0][0];       // wave-uniform base
            if (sarr == 0)
                gload_lds16(Kb + (size_t)(kt + r0 + sr) * 1024 + sc, dst);
            else
                gload_lds16(Vb + (size_t)(r0 + sr) * 8192 + kt + sc, dst);
        }
    };

    bf16x8 onesf;
#pragma unroll
    for (int j = 0; j < 8; j++) onesf[j] = (short)0x3F80;   // bf16 1.0

    f32x16 o[2], l_acc, fz;
#pragma unroll
    for (int r = 0; r < 16; r++) {
        o[0][r] = 0.f; o[1][r] = 0.f; l_acc[r] = 0.f; fz[r] = 0.f;
    }

    stage(0, 0);
    for (int kt = 0; kt < 2048; kt += 64) {
        const int cur = (kt >> 6) & 1;
        stage(cur ^ 1, (kt + 64) & 2047);   // last iter wraps: harmless re-stage
        asm volatile("s_waitcnt vmcnt(4)" ::: "memory");  // tile cur complete
        __builtin_amdgcn_s_barrier();
        __builtin_amdgcn_sched_barrier(0);

        // S^T[kv][q]: st[blk] covers kv = blk*32 + crow(reg,hi), q = l31
        f32x16 st[2];
#pragma unroll
        for (int blk = 0; blk < 2; blk++) {
#pragma unroll
            for (int slot = 0; slot < 4; slot++) {
                bf16x8 kf = *(const bf16x8*)
                    &lds[cur][0][blk * 32 + l31][(((slot << 1) | hi) ^ xr) * 8];
                st[blk] = (slot == 0) ? MFMA32(kf, qf[0], fz)
                                      : MFMA32(kf, qf[slot], st[blk]);
            }
        }

        // exp (log2-domain scores); row-sum via ones-MFMA below
#pragma unroll
        for (int blk = 0; blk < 2; blk++)
#pragma unroll
            for (int r = 0; r < 16; r++)
                st[blk][r] = fexp2(st[blk][r]);

        // P -> A-fragments (cvt_pk + permlane32_swap) fused with PV MFMAs
#pragma unroll
        for (int ks = 0; ks < 4; ks++) {
            const int blk = ks >> 1;
            const int rb  = (ks & 1) * 8;
            int A0 = cvtpk_bf16(st[blk][rb + 0], st[blk][rb + 1]);
            int A1 = cvtpk_bf16(st[blk][rb + 2], st[blk][rb + 3]);
            int B0 = cvtpk_bf16(st[blk][rb + 4], st[blk][rb + 5]);
            int B1 = cvtpk_bf16(st[blk][rb + 6], st[blk][rb + 7]);
            permswap(A0, B0);   // A0 -> dw0 (j0,j1), B0 -> dw2 (j4,j5)
            permswap(A1, B1);   // A1 -> dw1 (j2,j3), B1 -> dw3 (j6,j7)
            i32x4 paw; paw[0] = A0; paw[1] = A1; paw[2] = B0; paw[3] = B1;
            const bf16x8 pf = *(const bf16x8*)&paw;
            l_acc = MFMA32(pf, onesf, l_acc);   // row-sum on matrix pipe
#pragma unroll
            for (int dblk = 0; dblk < 2; dblk++) {
                bf16x8 vf = *(const bf16x8*)
                    &lds[cur][1][dblk * 32 + l31][(((ks << 1) | hi) ^ xr) * 8];
                o[dblk] = MFMA32(pf, vf, o[dblk]);
            }
        }

        asm volatile("s_waitcnt lgkmcnt(0)" ::: "memory");
        __builtin_amdgcn_sched_barrier(0);
        __builtin_amdgcn_s_barrier();
    }

    // l_acc[r] = l[qrow(r)] already in-lane: no cross-lane reduce needed.
#pragma unroll
    for (int r = 0; r < 16; r++) {
        const int qrow = (r & 3) + 8 * (r >> 2) + 4 * hi;
        const float inv = 1.f / l_acc[r];
#pragma unroll
        for (int dblk = 0; dblk < 2; dblk++)
            Aout[(size_t)(q0 + qrow) * 1024 + c0 + dblk * 32 + l31] =
                f2bf(o[dblk][r] * inv);
    }
}

// ---------------------------------------------------------------------------
extern "C" void kernel_launch(void* const* d_in, const int* in_sizes, int n_in,
                              void* d_out, int out_size, void* d_ws, size_t ws_size,
                              hipStream_t stream)
{
    const size_t MB = (size_t)1024 * 1024;
    char* ws = (char*)d_ws;

    int*   flagp = (int*)ws;                 // [0, 256)
    short* embC  = (short*)(ws + 1 * MB);    // 16 MB [8192][1024]
    short* wC[4] = { (short*)(ws + 17 * MB), (short*)(ws + 19 * MB),
                     (short*)(ws + 21 * MB), (short*)(ws + 23 * MB) };  // 2 MB ea
    short* bC[4] = { (short*)(ws + 25 * MB), (short*)(ws + 25 * MB + 4096),
                     (short*)(ws + 25 * MB + 8192), (short*)(ws + 25 * MB + 12288) };

    short *Qb, *Kb, *Vt, *Ab;
    if (ws_size >= 90 * MB) {
        Qb = (short*)(ws + 26 * MB);
        Kb = (short*)(ws + 42 * MB);
        Vt = (short*)(ws + 58 * MB);
        Ab = (short*)(ws + 74 * MB);
    } else {
        Qb = (short*)(ws + 26 * MB);
        Kb = (short*)d_out;      // dead after attention; final GEMM rewrites
        Vt = (short*)(ws + 42 * MB);
        Ab = Qb;                 // alias: safe per attn_kernel note
    }

    // Fused detect + all conversions: one launch (was 3).
    preprocess<<<6146, 256, 0, stream>>>(
        d_in[0], embC,
        d_in[1], d_in[3], d_in[5], d_in[7],
        d_in[2], d_in[4], d_in[6], d_in[8],
        wC[0], wC[1], wC[2], wC[3],
        bC[0], bC[1], bC[2], bC[3], flagp);

    dim3 blk(512);
    // Fused QKV; Q scale = log2(e)/8 (log2-domain softmax, see attn header).
    gemm256<<<dim3(256, 1, 3), blk, 0, stream>>>(
        embC, wC[0], wC[1], wC[2], bC[0], bC[1], bC[2],
        Qb, Kb, Vt, 0.18033688011112042f, 1.0f, 1.0f, 0, 0, 1, nullptr);

    attn_kernel<<<dim3(16, 64), dim3(256), 0, stream>>>(Qb, Kb, Vt, Ab);

    gemm256<<<dim3(256, 1, 1), blk, 0, stream>>>(
        Ab, wC[3], nullptr, nullptr, bC[3], nullptr, nullptr,
        d_out, nullptr, nullptr, 1.0f, 0.f, 0.f, 2, 0, 0, flagp);
}

// Round 12
// 294.664 us; speedup vs baseline: 1.1320x; 1.0046x over previous
//
#include <hip/hip_runtime.h>
#include <hip/hip_bf16.h>
#include <math.h>

// bf16 stored as short (raw bits); fp32 accumulate in MFMA.
using bf16x8 = __attribute__((ext_vector_type(8))) short;
using f32x4  = __attribute__((ext_vector_type(4))) float;
using f32x16 = __attribute__((ext_vector_type(16))) float;
using i32x4  = __attribute__((ext_vector_type(4))) int;
using i32x2  = __attribute__((ext_vector_type(2))) int;

#define MFMA32(a, b, c) __builtin_amdgcn_mfma_f32_32x32x16_bf16((a), (b), (c), 0, 0, 0)

__device__ __forceinline__ float bf2f(short s) {
    union { unsigned u; float f; } v;
    v.u = ((unsigned)(unsigned short)s) << 16;
    return v.f;
}
__device__ __forceinline__ short f2bf(float f) {
    union { float f; unsigned u; } v; v.f = f;
    unsigned r = v.u + 0x7FFF + ((v.u >> 16) & 1);  // round-to-nearest-even
    return (short)(r >> 16);
}
// Native packed f32->bf16 convert (RNE), 1 VALU op for 2 values.
__device__ __forceinline__ int cvtpk_bf16(float lo, float hi) {
    int r;
    asm("v_cvt_pk_bf16_f32 %0, %1, %2" : "=v"(r) : "v"(lo), "v"(hi));
    return r;
}
// v_permlane32_swap_b32: a'[l<32]=a[l], a'[32+i]=b[i]; b'[i]=a[32+i], b'[32+i]=b[32+i].
__device__ __forceinline__ void permswap(int &a, int &b) {
#if __has_builtin(__builtin_amdgcn_permlane32_swap)
    typedef unsigned u32x2v __attribute__((ext_vector_type(2)));
    u32x2v r = __builtin_amdgcn_permlane32_swap((unsigned)a, (unsigned)b, false, false);
    a = (int)r[0]; b = (int)r[1];
#else
    asm volatile("v_permlane32_swap_b32 %0, %1" : "+v"(a), "+v"(b));
#endif
}
// Raw 2^x (v_exp_f32). Q is pre-scaled by log2(e)/8 so this IS exp(score).
__device__ __forceinline__ float fexp2(float x) {
#if __has_builtin(__builtin_amdgcn_exp2f)
    return __builtin_amdgcn_exp2f(x);
#else
    return exp2f(x);
#endif
}

// Async global->LDS DMA, 16B per lane (LDS dest = wave base + lane*16).
__device__ __forceinline__ void gload_lds16(const void* g, void* l) {
    __builtin_amdgcn_global_load_lds(
        (const __attribute__((address_space(1))) void*)g,
        (__attribute__((address_space(3))) void*)l, 16, 0, 0);
}

// ---------------------------------------------------------------------------
// preprocess R17 (verified R11: -4us): detect + convert8 + convert_all fused.
// Per-block 256-sample dtype vote over the first 512 shorts of emb (binomial
// separation fp32~41/256 vs bf16~256/256; threshold 128). Block 0 writes the
// global flag for the out-proj GEMM's mode-2 epilogue.
// Grid: 4096 emb blocks + 2050 weight/bias blocks = 6146 x 256.
// ---------------------------------------------------------------------------
__global__ void preprocess(
    const void* __restrict__ emb, short* __restrict__ embC,
    const void* __restrict__ w0, const void* __restrict__ w1,
    const void* __restrict__ w2, const void* __restrict__ w3,
    const void* __restrict__ b0, const void* __restrict__ b1,
    const void* __restrict__ b2, const void* __restrict__ b3,
    short* dw0, short* dw1, short* dw2, short* dw3,
    short* db0, short* db1, short* db2, short* db3,
    int* flagp)
{
    __shared__ int vote;
    const int tid = threadIdx.x;
    if (tid == 0) vote = 0;
    __syncthreads();
    {
        unsigned short v = ((const unsigned short*)emb)[2 * tid];
        unsigned e = (v >> 7) & 0xFF;
        int c = (v == 0 || v == 0x8000u || (e >= 97 && e <= 137)) ? 1 : 0;
        atomicAdd(&vote, c);
    }
    __syncthreads();
    const int fl = vote > 128;
    if (blockIdx.x == 0 && tid == 0) *flagp = fl;

    const void* src; short* dst; int idx;
    if (blockIdx.x < 4096) {                    // embeddings: 1048576 n8
        src = emb; dst = embC; idx = blockIdx.x * 256 + tid;
    } else {
        int i = (blockIdx.x - 4096) * 256 + tid;
        if (i < 524288) {                       // weights: 4 x 131072 n8
            int w = i >> 17; idx = i & 131071;
            src = (w == 0) ? w0 : (w == 1) ? w1 : (w == 2) ? w2 : w3;
            dst = (w == 0) ? dw0 : (w == 1) ? dw1 : (w == 2) ? dw2 : dw3;
        } else {                                // biases: 4 x 128 n8
            int j = i - 524288; int b = j >> 7; idx = j & 127;
            src = (b == 0) ? b0 : (b == 1) ? b1 : (b == 2) ? b2 : b3;
            dst = (b == 0) ? db0 : (b == 1) ? db1 : (b == 2) ? db2 : db3;
        }
    }
    if (fl) {
        ((bf16x8*)dst)[idx] = ((const bf16x8*)src)[idx];
    } else {
        const float* f = (const float*)src + (size_t)idx * 8;
        bf16x8 o;
#pragma unroll
        for (int j = 0; j < 8; j++) o[j] = f2bf(f[j]);
        ((bf16x8*)dst)[idx] = o;
    }
}

// ---------------------------------------------------------------------------
// GEMM R18: R16 geometry (256x128, BK=64, 8 waves) + m201-style phase-split.
// The 2-barrier-per-tile R16 plateaued ~690-750 TF; catalog (m196/m218/m248)
// says the lever is fine phase interleave + counted waits + setprio (T3+T4,
// enabling T5). Per K-tile, TWO phases of 8 MFMA32 (64cy matrix work each):
//   P0: issue 4 A-gloads(t+1); vmcnt(4) [t's 6 are oldest -> all landed;
//       4 newest stay in flight]; barrier [cross-wave LDS visibility];
//       ds_read ks0/ks1; lgkmcnt(0)+sched_barrier; setprio(1); 8 MFMA;
//       setprio(0); barrier.
//   P1: ds_read ks2/ks3; issue 2 B-gloads(t+1); barrier; lgkmcnt(0)+
//       sched_barrier; setprio(1); 8 MFMA; setprio(0); barrier.
// vmcnt never 0 in the loop. All barrier/vmcnt counts wave-uniform (6
// loads/wave/tile: 4A+2B). Wrap-stage at t=15 lands in a dead buffer.
// Bank swizzle + XCD swizzle + fragment contracts unchanged (all verified).
// mode: 0 = bf16 natural, 1 = bf16 transposed (Vt), 2 = per *flag dtype.
// ---------------------------------------------------------------------------
__global__ __launch_bounds__(512) void gemm256(
    const short* __restrict__ A,
    const short* __restrict__ B0, const short* __restrict__ B1,
    const short* __restrict__ B2,
    const short* __restrict__ bias0, const short* __restrict__ bias1,
    const short* __restrict__ bias2,
    void* __restrict__ C0, void* __restrict__ C1, void* __restrict__ C2,
    float s0, float s1, float s2,
    int mode0, int mode1, int mode2,
    const int* __restrict__ flag)
{
    constexpr int M = 8192, N = 1024, Kd = 1024, BK = 64;
    __shared__ __align__(16) short Al[2][256][BK];   // 64 KB
    __shared__ __align__(16) short Bl[2][128][BK];   // 32 KB

    const int z = blockIdx.z;
    const short* B    = (z == 0) ? B0    : (z == 1) ? B1    : B2;
    const short* bias = (z == 0) ? bias0 : (z == 1) ? bias1 : bias2;
    void*  C     = (z == 0) ? C0 : (z == 1) ? C1 : C2;
    float  scale = (z == 0) ? s0 : (z == 1) ? s1 : s2;
    int    mode  = (z == 0) ? mode0 : (z == 1) ? mode1 : mode2;

    const int tid  = threadIdx.x;
    const int lane = tid & 63;
    const int wave = tid >> 6;          // 0..7
    const int l31  = lane & 31;
    const int hi   = lane >> 5;
    const int xr   = (l31 & 7) ^ ((l31 >> 3) & 3);   // read-side XOR (attn-proven)

    // XCD-aware bijective swizzle (256 blocks/z, 8 XCDs; XCD = bid%8).
    const int bid = blockIdx.x;
    const int swz = ((bid & 7) << 5) | (bid >> 3);
    const int m0 = (swz >> 3) * 256;
    const int n0 = (swz & 7) * 128;
    const int wm = (wave >> 1) * 64;    // 4 M-groups
    const int wn = (wave & 1) * 64;     // 2 N-groups

    // staging: lane l -> row r0+(l>>3), LDS chunk l&7
    const int sr  = lane >> 3;
    const int scb = (lane & 7) ^ sr;

    int fl = 1;
    if (mode == 2) fl = *flag;

    f32x16 acc[2][2];
#pragma unroll
    for (int i = 0; i < 2; i++)
#pragma unroll
        for (int j = 0; j < 2; j++)
#pragma unroll
            for (int r = 0; r < 16; r++) acc[i][j][r] = 0.f;

    auto stageA = [&](int bufi, int k) {
#pragma unroll
        for (int t = 0; t < 4; t++) {
            const int r0 = wave * 32 + t * 8;           // (r0>>3)&3 == t
            gload_lds16(A + (size_t)(m0 + r0 + sr) * Kd + k + ((scb ^ t) & 7) * 8,
                        &Al[bufi][r0][0]);
        }
    };
    auto stageB = [&](int bufi, int k) {
#pragma unroll
        for (int t = 0; t < 2; t++) {
            const int r0 = wave * 16 + t * 8;           // (r0>>3)&3 == (2w+t)&3
            const int tb = (wave * 2 + t) & 3;
            gload_lds16(B + (size_t)(n0 + r0 + sr) * Kd + k + ((scb ^ tb) & 7) * 8,
                        &Bl[bufi][r0][0]);
        }
    };

    stageA(0, 0);
    stageB(0, 0);
    for (int k0 = 0; k0 < Kd; k0 += BK) {
        const int cur = (k0 >> 6) & 1;
        const int kn  = (k0 + BK) & (Kd - 1);   // wraps at tail: dead buffer

        // ---- Phase 0: A-prefetch + ks0/ks1 ----
        stageA(cur ^ 1, kn);                    // 4 loads (newest)
        asm volatile("s_waitcnt vmcnt(4)" ::: "memory");  // tile cur landed
        __builtin_amdgcn_s_barrier();           // cross-wave visibility
        __builtin_amdgcn_sched_barrier(0);

        bf16x8 a0[2], a1[2], b0[2], b1[2];
#pragma unroll
        for (int ks = 0; ks < 2; ks++) {
            const int rc = (((ks << 1) | hi) ^ xr) * 8;
            a0[ks] = *(const bf16x8*)(&Al[cur][wm + l31][rc]);
            a1[ks] = *(const bf16x8*)(&Al[cur][wm + 32 + l31][rc]);
            b0[ks] = *(const bf16x8*)(&Bl[cur][wn + l31][rc]);
            b1[ks] = *(const bf16x8*)(&Bl[cur][wn + 32 + l31][rc]);
        }
        asm volatile("s_waitcnt lgkmcnt(0)" ::: "memory");
        __builtin_amdgcn_sched_barrier(0);
        __builtin_amdgcn_s_setprio(1);
#pragma unroll
        for (int ks = 0; ks < 2; ks++) {
            acc[0][0] = MFMA32(a0[ks], b0[ks], acc[0][0]);
            acc[0][1] = MFMA32(a0[ks], b1[ks], acc[0][1]);
            acc[1][0] = MFMA32(a1[ks], b0[ks], acc[1][0]);
            acc[1][1] = MFMA32(a1[ks], b1[ks], acc[1][1]);
        }
        __builtin_amdgcn_s_setprio(0);
        __builtin_amdgcn_s_barrier();

        // ---- Phase 1: ks2/ks3 + B-prefetch ----
#pragma unroll
        for (int ks = 0; ks < 2; ks++) {
            const int rc = ((((ks + 2) << 1) | hi) ^ xr) * 8;
            a0[ks] = *(const bf16x8*)(&Al[cur][wm + l31][rc]);
            a1[ks] = *(const bf16x8*)(&Al[cur][wm + 32 + l31][rc]);
            b0[ks] = *(const bf16x8*)(&Bl[cur][wn + l31][rc]);
            b1[ks] = *(const bf16x8*)(&Bl[cur][wn + 32 + l31][rc]);
        }
        stageB(cur ^ 1, kn);                    // 2 loads
        __builtin_amdgcn_s_barrier();
        asm volatile("s_waitcnt lgkmcnt(0)" ::: "memory");
        __builtin_amdgcn_sched_barrier(0);
        __builtin_amdgcn_s_setprio(1);
#pragma unroll
        for (int ks = 0; ks < 2; ks++) {
            acc[0][0] = MFMA32(a0[ks], b0[ks], acc[0][0]);
            acc[0][1] = MFMA32(a0[ks], b1[ks], acc[0][1]);
            acc[1][0] = MFMA32(a1[ks], b0[ks], acc[1][0]);
            acc[1][1] = MFMA32(a1[ks], b1[ks], acc[1][1]);
        }
        __builtin_amdgcn_s_setprio(0);
        __builtin_amdgcn_s_barrier();
    }

    if (mode == 1) {
        // Vt: C[col][row]; rows g*8+4*hi+0..3 consecutive -> one 8B store.
#pragma unroll
        for (int j = 0; j < 2; j++) {
            const int col = n0 + wn + j * 32 + l31;
            const float bv = bf2f(bias[col]);
#pragma unroll
            for (int i = 0; i < 2; i++) {
#pragma unroll
                for (int g = 0; g < 4; g++) {
                    const int row = m0 + wm + i * 32 + g * 8 + 4 * hi;
                    const float v0 = (acc[i][j][g * 4 + 0] + bv) * scale;
                    const float v1 = (acc[i][j][g * 4 + 1] + bv) * scale;
                    const float v2 = (acc[i][j][g * 4 + 2] + bv) * scale;
                    const float v3 = (acc[i][j][g * 4 + 3] + bv) * scale;
                    i32x2 dd;
                    dd[0] = cvtpk_bf16(v0, v1);
                    dd[1] = cvtpk_bf16(v2, v3);
                    *(i32x2*)((short*)C + (size_t)col * M + row) = dd;
                }
            }
        }
    } else {
#pragma unroll
        for (int j = 0; j < 2; j++) {
            const int col = n0 + wn + j * 32 + l31;
            const float bv = bf2f(bias[col]);
#pragma unroll
            for (int i = 0; i < 2; i++) {
#pragma unroll
                for (int r = 0; r < 16; r++) {
                    const int row = m0 + wm + i * 32 + (r & 3) + 8 * (r >> 2) + 4 * hi;
                    const float v = (acc[i][j][r] + bv) * scale;
                    if (mode == 0) ((short*)C)[(size_t)row * N + col] = f2bf(v);
                    else {
                        if (fl) ((short*)C)[(size_t)row * N + col] = f2bf(v);
                        else    ((float*)C)[(size_t)row * N + col] = v;
                    }
                }
            }
        }
    }
}

// ---------------------------------------------------------------------------
// Flash attention R13 (reverted to 4-round-stable form; R11's zero-C trick
// measured neutral-to-negative and is removed). 95us / MfmaUtil 40% /
// conflicts 0: 32x32 swapped-operand; both-sides XOR bank fix; ones-MFMA
// row-sum (l_acc[r] = l[qrow(r)] in-lane); gload_lds dbuf + counted vmcnt(4).
// S^T = mfma(K, Q): lane holds P[q=lane&31][kv subset] lane-locally.
// Aout may alias Q: each wave reads only the 32 Q rows it alone writes.
// ---------------------------------------------------------------------------
__global__ __launch_bounds__(256) void attn_kernel(
    const short* Q, const short* __restrict__ K,
    const short* __restrict__ Vt, short* Aout)
{
    // [buf][0]=K tile [kv 0..63][64 c], [buf][1]=V tile [d 0..63][64 kv]
    __shared__ __align__(16) short lds[2][2][64][64];   // 32 KiB

    const int tid  = threadIdx.x;
    const int lane = tid & 63;
    const int wave = tid >> 6;
    const int l31  = lane & 31;
    const int hi   = lane >> 5;
    const int xr   = (l31 & 7) ^ ((l31 >> 3) & 3);   // read-side XOR

    const int qt = blockIdx.x;
    const int bh = blockIdx.y;
    const int b  = bh >> 4, h = bh & 15;
    const int q0 = b * 2048 + qt * 128 + wave * 32;
    const int c0 = h * 64;

    // staging geometry: lane l -> row r0+(l>>3), LDS chunk l&7;
    // source chunk = (l&7) ^ (l>>3) ^ t  (t = (r0>>3)&3 of the 8-row group)
    const int sr  = lane >> 3;
    const int scb = (lane & 7) ^ sr;
    const int sarr = wave >> 1;                // waves 0,1 -> K; 2,3 -> V

    const short* Kb = K  + (size_t)(b * 2048) * 1024 + c0;
    const short* Vb = Vt + (size_t)c0 * 8192 + b * 2048;

    // Q as B-fragments: lane holds Q[q=l31][c = slot*16 + hi*8 + 0..7]
    bf16x8 qf[4];
#pragma unroll
    for (int slot = 0; slot < 4; slot++)
        qf[slot] = *(const bf16x8*)(Q + (size_t)(q0 + l31) * 1024 + c0 + slot * 16 + hi * 8);

    auto stage = [&](int bufi, int kt) {
#pragma unroll
        for (int t = 0; t < 4; t++) {
            const int r0 = ((wave & 1) * 4 + t) * 8;
            const int sc = (scb ^ t) * 8;
            short* dst = &lds[bufi][sarr][r0][0];       // wave-uniform base
            if (sarr == 0)
                gload_lds16(Kb + (size_t)(kt + r0 + sr) * 1024 + sc, dst);
            else
                gload_lds16(Vb + (size_t)(r0 + sr) * 8192 + kt + sc, dst);
        }
    };

    bf16x8 onesf;
#pragma unroll
    for (int j = 0; j < 8; j++) onesf[j] = (short)0x3F80;   // bf16 1.0

    f32x16 o[2], l_acc;
#pragma unroll
    for (int r = 0; r < 16; r++) { o[0][r] = 0.f; o[1][r] = 0.f; l_acc[r] = 0.f; }

    stage(0, 0);
    for (int kt = 0; kt < 2048; kt += 64) {
        const int cur = (kt >> 6) & 1;
        stage(cur ^ 1, (kt + 64) & 2047);   // last iter wraps: harmless re-stage
        asm volatile("s_waitcnt vmcnt(4)" ::: "memory");  // tile cur complete
        __builtin_amdgcn_s_barrier();
        __builtin_amdgcn_sched_barrier(0);

        // S^T[kv][q]: st[blk] covers kv = blk*32 + crow(reg,hi), q = l31
        f32x16 st[2];
#pragma unroll
        for (int blk = 0; blk < 2; blk++) {
#pragma unroll
            for (int r = 0; r < 16; r++) st[blk][r] = 0.f;
#pragma unroll
            for (int slot = 0; slot < 4; slot++) {
                bf16x8 kf = *(const bf16x8*)
                    &lds[cur][0][blk * 32 + l31][(((slot << 1) | hi) ^ xr) * 8];
                st[blk] = MFMA32(kf, qf[slot], st[blk]);
            }
        }

        // exp (log2-domain scores); row-sum via ones-MFMA below
#pragma unroll
        for (int blk = 0; blk < 2; blk++)
#pragma unroll
            for (int r = 0; r < 16; r++)
                st[blk][r] = fexp2(st[blk][r]);

        // P -> A-fragments (cvt_pk + permlane32_swap) fused with PV MFMAs
#pragma unroll
        for (int ks = 0; ks < 4; ks++) {
            const int blk = ks >> 1;
            const int rb  = (ks & 1) * 8;
            int A0 = cvtpk_bf16(st[blk][rb + 0], st[blk][rb + 1]);
            int A1 = cvtpk_bf16(st[blk][rb + 2], st[blk][rb + 3]);
            int B0 = cvtpk_bf16(st[blk][rb + 4], st[blk][rb + 5]);
            int B1 = cvtpk_bf16(st[blk][rb + 6], st[blk][rb + 7]);
            permswap(A0, B0);   // A0 -> dw0 (j0,j1), B0 -> dw2 (j4,j5)
            permswap(A1, B1);   // A1 -> dw1 (j2,j3), B1 -> dw3 (j6,j7)
            i32x4 paw; paw[0] = A0; paw[1] = A1; paw[2] = B0; paw[3] = B1;
            const bf16x8 pf = *(const bf16x8*)&paw;
            l_acc = MFMA32(pf, onesf, l_acc);   // row-sum on matrix pipe
#pragma unroll
            for (int dblk = 0; dblk < 2; dblk++) {
                bf16x8 vf = *(const bf16x8*)
                    &lds[cur][1][dblk * 32 + l31][(((ks << 1) | hi) ^ xr) * 8];
                o[dblk] = MFMA32(pf, vf, o[dblk]);
            }
        }

        asm volatile("s_waitcnt lgkmcnt(0)" ::: "memory");
        __builtin_amdgcn_sched_barrier(0);
        __builtin_amdgcn_s_barrier();
    }

    // l_acc[r] = l[qrow(r)] already in-lane: no cross-lane reduce needed.
#pragma unroll
    for (int r = 0; r < 16; r++) {
        const int qrow = (r & 3) + 8 * (r >> 2) + 4 * hi;
        const float inv = 1.f / l_acc[r];
#pragma unroll
        for (int dblk = 0; dblk < 2; dblk++)
            Aout[(size_t)(q0 + qrow) * 1024 + c0 + dblk * 32 + l31] =
                f2bf(o[dblk][r] * inv);
    }
}

// ---------------------------------------------------------------------------
extern "C" void kernel_launch(void* const* d_in, const int* in_sizes, int n_in,
                              void* d_out, int out_size, void* d_ws, size_t ws_size,
                              hipStream_t stream)
{
    const size_t MB = (size_t)1024 * 1024;
    char* ws = (char*)d_ws;

    int*   flagp = (int*)ws;                 // [0, 256)
    short* embC  = (short*)(ws + 1 * MB);    // 16 MB [8192][1024]
    short* wC[4] = { (short*)(ws + 17 * MB), (short*)(ws + 19 * MB),
                     (short*)(ws + 21 * MB), (short*)(ws + 23 * MB) };  // 2 MB ea
    short* bC[4] = { (short*)(ws + 25 * MB), (short*)(ws + 25 * MB + 4096),
                     (short*)(ws + 25 * MB + 8192), (short*)(ws + 25 * MB + 12288) };

    short *Qb, *Kb, *Vt, *Ab;
    if (ws_size >= 90 * MB) {
        Qb = (short*)(ws + 26 * MB);
        Kb = (short*)(ws + 42 * MB);
        Vt = (short*)(ws + 58 * MB);
        Ab = (short*)(ws + 74 * MB);
    } else {
        Qb = (short*)(ws + 26 * MB);
        Kb = (short*)d_out;      // dead after attention; final GEMM rewrites
        Vt = (short*)(ws + 42 * MB);
        Ab = Qb;                 // alias: safe per attn_kernel note
    }

    // Fused detect + all conversions: one launch.
    preprocess<<<6146, 256, 0, stream>>>(
        d_in[0], embC,
        d_in[1], d_in[3], d_in[5], d_in[7],
        d_in[2], d_in[4], d_in[6], d_in[8],
        wC[0], wC[1], wC[2], wC[3],
        bC[0], bC[1], bC[2], bC[3], flagp);

    dim3 blk(512);
    // Fused QKV; Q scale = log2(e)/8 (log2-domain softmax, see attn header).
    gemm256<<<dim3(256, 1, 3), blk, 0, stream>>>(
        embC, wC[0], wC[1], wC[2], bC[0], bC[1], bC[2],
        Qb, Kb, Vt, 0.18033688011112042f, 1.0f, 1.0f, 0, 0, 1, nullptr);

    attn_kernel<<<dim3(16, 64), dim3(256), 0, stream>>>(Qb, Kb, Vt, Ab);

    gemm256<<<dim3(256, 1, 1), blk, 0, stream>>>(
        Ab, wC[3], nullptr, nullptr, bC[3], nullptr, nullptr,
        d_out, nullptr, nullptr, 1.0f, 0.f, 0.f, 2, 0, 0, flagp);
}